// Round 3
// baseline (312.019 us; speedup 1.0000x reference)
//
#include <hip/hip_runtime.h>

typedef __bf16 bf16;
typedef __bf16 bf16x8 __attribute__((ext_vector_type(8)));
typedef float  f32x4  __attribute__((ext_vector_type(4)));

#define DEVI __device__ __forceinline__

static constexpr int   BATCH = 256;
static constexpr int   SEQ   = 256;
static constexpr int   CH    = 192;
static constexpr int   NH    = 6;
static constexpr int   AG    = 49;
static constexpr float QK_SCALE = 0.17677669529663687f;  // 32^-0.5

// ---- adaptive-avg-pool 16 -> 7: inverse bin tables (idx -> (bin, weight) x {1,2}) ----
__device__ constexpr int   PPN[16]  = {1,1,2,1,2,1,2,1,1,2,1,2,1,2,1,1};
__device__ constexpr int   PPB0[16] = {0,0,0,1,1,2,2,3,3,3,4,4,5,5,6,6};
__device__ constexpr int   PPB1[16] = {0,0,1,0,2,0,3,0,0,4,0,5,0,6,0,0};
__device__ constexpr float PPW0[16] = {1.f/3.f,1.f/3.f,1.f/3.f,1.f/3.f,1.f/3.f,1.f/3.f,1.f/3.f,0.25f,0.25f,0.25f,
                                       1.f/3.f,1.f/3.f,1.f/3.f,1.f/3.f,1.f/3.f,1.f/3.f};
__device__ constexpr float PPW1[16] = {0.f,0.f,1.f/3.f,0.f,1.f/3.f,0.f,0.25f,0.f,0.f,1.f/3.f,
                                       0.f,1.f/3.f,0.f,1.f/3.f,0.f,0.f};

// ---------------------------------------------------------------------------
DEVI float bilin7(const float* m, int i, int j) {
  float sh = (i + 0.5f) * 0.4375f - 0.5f; sh = sh < 0.f ? 0.f : sh;
  float sw = (j + 0.5f) * 0.4375f - 0.5f; sw = sw < 0.f ? 0.f : sw;
  int i0 = (int)sh; if (i0 > 6) i0 = 6;
  int j0 = (int)sw; if (j0 > 6) j0 = 6;
  int i1 = i0 + 1;  if (i1 > 6) i1 = 6;
  int j1 = j0 + 1;  if (j1 > 6) j1 = 6;
  float th = sh - (float)i0, tw = sw - (float)j0;
  float v00 = m[i0*7 + j0], v01 = m[i0*7 + j1];
  float v10 = m[i1*7 + j0], v11 = m[i1*7 + j1];
  return (v00*(1.f-tw) + v01*tw)*(1.f-th) + (v10*(1.f-tw) + v11*tw)*th;
}

// ---------------------------------------------------------------------------
// K1: weights->bf16, pb[h][a][n], ab[h][n][a], zero pads of a1/a2
__global__ void k_prep(const float* Wq, const float* Wk, const float* Wv,
                       const float* Wa1, const float* Wa2, const float* Wp,
                       const float* an_bias, const float* na_bias,
                       const float* ah_bias, const float* aw_bias,
                       const float* ha_bias, const float* wa_bias,
                       bf16* wsW, float* pb, float* ab, bf16* a1, bf16* a2) {
  int gid = blockIdx.x * 256 + threadIdx.x;
  if (gid < 221184) {
    int mi = gid / 36864, r = gid - mi * 36864;
    const float* W = (mi == 0 ? Wq : mi == 1 ? Wk : mi == 2 ? Wv :
                      mi == 3 ? Wa1 : mi == 4 ? Wa2 : Wp);
    wsW[gid] = (bf16)W[r];
  } else if (gid < 296448) {                // pb: [h][49][256]
    int r = gid - 221184;
    int n = r & 255, ha = r >> 8;
    int i = n >> 4, j = n & 15;
    float val = bilin7(an_bias + (size_t)ha * 49, i, j)
              + ah_bias[ha * 16 + i] + aw_bias[ha * 16 + j];
    pb[r] = val;
  } else if (gid < 371712) {                // ab: [h][256][49]
    int r = gid - 296448;
    int a = r % 49, hn = r / 49;
    int n = hn & 255, hh = hn >> 8;
    int i = n >> 4, j = n & 15;
    float val = bilin7(na_bias + (size_t)(hh * 49 + a) * 49, i, j)
              + ha_bias[(hh * 16 + i) * 49 + a] + wa_bias[(hh * 16 + j) * 49 + a];
    ab[r] = val;
  } else if (gid < 396288) {                // zero 64 pad rows of a1,a2
    int r = gid - 371712;
    if (r < 12288) a1[(size_t)12544 * CH + r] = (bf16)0.f;
    else           a2[(size_t)12544 * CH + (r - 12288)] = (bf16)0.f;
  }
}

// ---------------------------------------------------------------------------
// K2: adaptive 16x16 -> 7x7 avg pool. grid (256 b, 2 which), 192 thr:
// thread = (ihalf 0..1) x (channel-pair 0..95); float2 loads; 4 local p-bins;
// p=3 overlap merged through LDS.
__global__ __launch_bounds__(192) void k_pool(
    const float* xC1, const float* xC2, bf16* pooled1, bf16* pooled2) {
  __shared__ float lred[7][192];
  const int b = blockIdx.x, which = blockIdx.y, t = threadIdx.x;
  const int c2 = t % 96, ih = t / 96;
  const float* src = (which ? xC2 : xC1) + (size_t)b * SEQ * CH + 2 * c2;
  bf16* dst = (which ? pooled2 : pooled1) + (size_t)b * AG * CH + 2 * c2;

  float accx[4][7], accy[4][7];
  #pragma unroll
  for (int p = 0; p < 4; ++p)
    #pragma unroll
    for (int q = 0; q < 7; ++q) { accx[p][q] = 0.f; accy[p][q] = 0.f; }

  #pragma unroll
  for (int il = 0; il < 8; ++il) {
    const int i = ih * 8 + il;
    float jqx[7] = {0,0,0,0,0,0,0}, jqy[7] = {0,0,0,0,0,0,0};
    #pragma unroll
    for (int j = 0; j < 16; ++j) {
      float2 x = *(const float2*)(src + (size_t)(i * 16 + j) * CH);
      jqx[PPB0[j]] += PPW0[j] * x.x;  jqy[PPB0[j]] += PPW0[j] * x.y;
      if (PPN[j] == 2) { jqx[PPB1[j]] += PPW1[j] * x.x;  jqy[PPB1[j]] += PPW1[j] * x.y; }
    }
    const int p0 = PPB0[i] - 3 * ih;   // local bin 0..3
    const float w0 = PPW0[i];
    #pragma unroll
    for (int q = 0; q < 7; ++q) { accx[p0][q] += w0 * jqx[q]; accy[p0][q] += w0 * jqy[q]; }
    if (PPN[i] == 2) {
      const int p1 = PPB1[i] - 3 * ih;
      const float w1 = PPW1[i];
      #pragma unroll
      for (int q = 0; q < 7; ++q) { accx[p1][q] += w1 * jqx[q]; accy[p1][q] += w1 * jqy[q]; }
    }
  }
  // merge global p=3 (half0 local 3  <-  half1 local 0)
  if (ih == 1) {
    #pragma unroll
    for (int q = 0; q < 7; ++q) {
      lred[q][2 * c2] = accx[0][q]; lred[q][2 * c2 + 1] = accy[0][q];
    }
  }
  __syncthreads();
  if (ih == 0) {
    #pragma unroll
    for (int q = 0; q < 7; ++q) {
      accx[3][q] += lred[q][2 * c2]; accy[3][q] += lred[q][2 * c2 + 1];
    }
  }
  const int lp0 = ih ? 1 : 0, np = ih ? 3 : 4, gb = ih ? 4 : 0;
  for (int lp = 0; lp < np; ++lp) {
    #pragma unroll
    for (int q = 0; q < 7; ++q) {
      const int a = (gb + lp) * 7 + q;
      union { bf16 e[2]; unsigned u; } u;
      u.e[0] = (bf16)accx[lp0 + lp][q];
      u.e[1] = (bf16)accy[lp0 + lp][q];
      *(unsigned*)&dst[(size_t)a * CH] = u.u;
    }
  }
}

// ---------------------------------------------------------------------------
// K3: fused q/k/v projection. grid 2048 (32-row tiles), 256 thr = 4 waves.
// Single-shot K=192 in LDS; jobs processed sequentially (small acc footprint);
// outputs staged through LDS for wide coalesced bf16 stores.
__global__ __launch_bounds__(256, 4) void k_gemm3(
    const float* xF1, const float* xC2, const float* xC1,
    const bf16* wsW, const float* bq, const float* bk, const float* bv,
    bf16* qO, bf16* kO, bf16* vO) {
  __shared__ bf16 sT[3][32][200] __attribute__((aligned(16)));   // 38,400 B
  const int tid = threadIdx.x, lane = tid & 63, wid = tid >> 6;
  const int l15 = lane & 15, lg = lane >> 4;
  const int m0 = blockIdx.x * 32;
  const int srow = tid >> 3, chunk = tid & 7;          // 32 rows x 8 chunks of 24

  // ---- stage: 24 floats per input per thread, fused combos -> LDS ----
  {
    const size_t rb = (size_t)(m0 + srow) * CH + chunk * 24;
    const float4* pF = (const float4*)(xF1 + rb);
    const float4* p2 = (const float4*)(xC2 + rb);
    const float4* p1 = (const float4*)(xC1 + rb);
    #pragma unroll
    for (int g = 0; g < 3; ++g) {
      float ff[8], f2[8], f1[8];
      *(float4*)&ff[0] = pF[2 * g]; *(float4*)&ff[4] = pF[2 * g + 1];
      *(float4*)&f2[0] = p2[2 * g]; *(float4*)&f2[4] = p2[2 * g + 1];
      *(float4*)&f1[0] = p1[2 * g]; *(float4*)&f1[4] = p1[2 * g + 1];
      bf16x8 tq, tk, tv;
      #pragma unroll
      for (int e = 0; e < 8; ++e) {
        const float d = f2[e] - f1[e];
        tq[e] = (bf16)ff[e];
        tk[e] = (bf16)(ff[e] + d);
        tv[e] = (bf16)d;
      }
      *(bf16x8*)&sT[0][srow][chunk * 24 + 8 * g] = tq;
      *(bf16x8*)&sT[1][srow][chunk * 24 + 8 * g] = tk;
      *(bf16x8*)&sT[2][srow][chunk * 24 + 8 * g] = tv;
    }
  }
  __syncthreads();

  #pragma unroll 1
  for (int job = 0; job < 3; ++job) {
    const bf16*  Wj   = wsW + job * 36864;
    const float* bias = (job == 0) ? bq : (job == 1) ? bk : bv;
    bf16*        outp = (job == 0) ? qO : (job == 1) ? kO : vO;

    f32x4 acc[2][3];
    #pragma unroll
    for (int rt = 0; rt < 2; ++rt)
      #pragma unroll
      for (int ct = 0; ct < 3; ++ct) acc[rt][ct] = f32x4{0.f, 0.f, 0.f, 0.f};

    #pragma unroll
    for (int kk = 0; kk < 6; ++kk) {
      bf16x8 af0 = *(const bf16x8*)&sT[job][l15][kk * 32 + 8 * lg];
      bf16x8 af1 = *(const bf16x8*)&sT[job][16 + l15][kk * 32 + 8 * lg];
      #pragma unroll
      for (int ct = 0; ct < 3; ++ct) {
        const int ncol = 48 * wid + 16 * ct + l15;
        bf16x8 bfr = *(const bf16x8*)&Wj[(size_t)ncol * CH + kk * 32 + 8 * lg];
        acc[0][ct] = __builtin_amdgcn_mfma_f32_16x16x32_bf16(af0, bfr, acc[0][ct], 0, 0, 0);
        acc[1][ct] = __builtin_amdgcn_mfma_f32_16x16x32_bf16(af1, bfr, acc[1][ct], 0, 0, 0);
      }
    }
    __syncthreads();   // all waves done reading sT[job] -> reuse as output tile
    #pragma unroll
    for (int ct = 0; ct < 3; ++ct) {
      const int col = 48 * wid + 16 * ct + l15;
      const float bb = bias[col];
      #pragma unroll
      for (int rt = 0; rt < 2; ++rt)
        #pragma unroll
        for (int r = 0; r < 4; ++r)
          sT[job][16 * rt + 4 * lg + r][col] = (bf16)(acc[rt][ct][r] + bb);
    }
    __syncthreads();
    // wide coalesced store: 48 B per thread
    {
      bf16* orow = outp + (size_t)(m0 + srow) * CH + chunk * 24;
      #pragma unroll
      for (int g = 0; g < 3; ++g)
        *(bf16x8*)&orow[8 * g] = *(const bf16x8*)&sT[job][srow][chunk * 24 + 8 * g];
    }
  }
}

// ---------------------------------------------------------------------------
// shared GEMM body (used by k_gemm2 only): tile 128x192, 4 waves
DEVI void gemm_body(const bf16* Asrc, const bf16* W, const float* bias,
                    bf16* outp, int m0, bf16 (*sA)[72]) {
  const int tid = threadIdx.x, lane = tid & 63, wid = tid >> 6;
  const int l15 = lane & 15, lg = lane >> 4;
  const int wr = wid >> 1, wc = wid & 1;
  const int srow = tid >> 1, shalf = tid & 1;

  f32x4 acc[4][6];
  #pragma unroll
  for (int a = 0; a < 4; ++a)
    #pragma unroll
    for (int b2 = 0; b2 < 6; ++b2) acc[a][b2] = f32x4{0.f, 0.f, 0.f, 0.f};

  for (int ks = 0; ks < 3; ++ks) {
    const int k0 = ks * 64;
    const uint4* src = (const uint4*)(Asrc + (size_t)(m0 + srow) * CH + k0 + shalf * 32);
    #pragma unroll
    for (int i2 = 0; i2 < 4; ++i2)
      *(uint4*)&sA[srow][shalf * 32 + 8 * i2] = src[i2];
    __syncthreads();
    #pragma unroll
    for (int kk = 0; kk < 64; kk += 32) {
      bf16x8 af[4];
      #pragma unroll
      for (int rt = 0; rt < 4; ++rt)
        af[rt] = *(const bf16x8*)&sA[64 * wr + 16 * rt + l15][kk + 8 * lg];
      #pragma unroll
      for (int ct = 0; ct < 6; ++ct) {
        const int ncol = 96 * wc + 16 * ct + l15;
        bf16x8 bfr = *(const bf16x8*)&W[(size_t)ncol * CH + k0 + kk + 8 * lg];
        #pragma unroll
        for (int rt = 0; rt < 4; ++rt)
          acc[rt][ct] = __builtin_amdgcn_mfma_f32_16x16x32_bf16(af[rt], bfr, acc[rt][ct], 0, 0, 0);
      }
    }
    __syncthreads();
  }
  #pragma unroll
  for (int ct = 0; ct < 6; ++ct) {
    const int col = 96 * wc + 16 * ct + l15;
    const float bb = bias[col];
    #pragma unroll
    for (int rt = 0; rt < 4; ++rt) {
      const size_t rbase = (size_t)(m0 + 64 * wr + 16 * rt + 4 * lg);
      #pragma unroll
      for (int r = 0; r < 4; ++r)
        outp[(rbase + r) * CH + col] = (bf16)(acc[rt][ct][r] + bb);
    }
  }
}

// K4: a1/a2 projections (98 tiles x 2 jobs)
__global__ __launch_bounds__(256, 2) void k_gemm2(
    const bf16* pooled1, const bf16* pooled2, const bf16* wsW,
    const float* ba1, const float* ba2, bf16* a1, bf16* a2) {
  __shared__ bf16 sA[128][72] __attribute__((aligned(16)));
  const int m0 = blockIdx.x * 128;
  if (blockIdx.y == 0) gemm_body(pooled1, wsW + 3 * 36864, ba1, a1, m0, sA);
  else                 gemm_body(pooled2, wsW + 4 * 36864, ba2, a2, m0, sA);
}

// ---------------------------------------------------------------------------
// K7: output projection, fp32 out. Single-shot 32-row tiles, 2048 blocks.
__global__ __launch_bounds__(256, 4) void k_gemm_out(
    const bf16* xsum, const bf16* Wp, const float* bp, float* out) {
  __shared__ char smem[25088] __attribute__((aligned(16)));
  bf16  (*sA)[200] = reinterpret_cast<bf16 (*)[200]>(smem);   // 12,800 B
  float (*sO)[196] = reinterpret_cast<float (*)[196]>(smem);  // 25,088 B
  const int tid = threadIdx.x, lane = tid & 63, wid = tid >> 6;
  const int l15 = lane & 15, lg = lane >> 4;
  const int m0 = blockIdx.x * 32;
  const int srow = tid >> 3, chunk = tid & 7;

  {
    const bf16* arow = xsum + (size_t)(m0 + srow) * CH + chunk * 24;
    #pragma unroll
    for (int g = 0; g < 3; ++g)
      *(bf16x8*)&sA[srow][chunk * 24 + 8 * g] = *(const bf16x8*)&arow[8 * g];
  }
  __syncthreads();

  f32x4 acc[2][3];
  #pragma unroll
  for (int rt = 0; rt < 2; ++rt)
    #pragma unroll
    for (int ct = 0; ct < 3; ++ct) acc[rt][ct] = f32x4{0.f, 0.f, 0.f, 0.f};

  #pragma unroll
  for (int kk = 0; kk < 6; ++kk) {
    bf16x8 af0 = *(const bf16x8*)&sA[l15][kk * 32 + 8 * lg];
    bf16x8 af1 = *(const bf16x8*)&sA[16 + l15][kk * 32 + 8 * lg];
    #pragma unroll
    for (int ct = 0; ct < 3; ++ct) {
      const int ncol = 48 * wid + 16 * ct + l15;
      bf16x8 bfr = *(const bf16x8*)&Wp[(size_t)ncol * CH + kk * 32 + 8 * lg];
      acc[0][ct] = __builtin_amdgcn_mfma_f32_16x16x32_bf16(af0, bfr, acc[0][ct], 0, 0, 0);
      acc[1][ct] = __builtin_amdgcn_mfma_f32_16x16x32_bf16(af1, bfr, acc[1][ct], 0, 0, 0);
    }
  }
  __syncthreads();   // sA dead
  #pragma unroll
  for (int ct = 0; ct < 3; ++ct) {
    const int col = 48 * wid + 16 * ct + l15;
    const float bb = bp[col];
    #pragma unroll
    for (int rt = 0; rt < 2; ++rt)
      #pragma unroll
      for (int r = 0; r < 4; ++r)
        sO[16 * rt + 4 * lg + r][col] = acc[rt][ct][r] + bb;
  }
  __syncthreads();
  {
    float* orow = out + (size_t)(m0 + srow) * CH + chunk * 24;
    #pragma unroll
    for (int g = 0; g < 6; ++g)
      *(float4*)&orow[4 * g] = *(const float4*)&sO[srow][chunk * 24 + 4 * g];
  }
}

// ---------------------------------------------------------------------------
// K5: fused two-stage agent attention per (b, h). 256 threads = 4 waves.
__global__ __launch_bounds__(256, 2) void k_attn(
    const bf16* q, const bf16* k, const bf16* v,
    const bf16* a1, const bf16* a2, const float* pb, const float* ab,
    bf16* xout) {
  const int h = blockIdx.x, b = blockIdx.y;
  __shared__ char uSmem[36864] __attribute__((aligned(16)));   // log1[64][264] | log2[256][72]
  bf16 (*log1)[264] = reinterpret_cast<bf16 (*)[264]>(uSmem);
  bf16 (*log2)[72]  = reinterpret_cast<bf16 (*)[72]>(uSmem);
  __shared__ bf16 sVT[32][264] __attribute__((aligned(16)));   // v transposed [d][n]
  __shared__ bf16 sAVT[32][72] __attribute__((aligned(16)));   // agent_v^T [d][a(64)]
  __shared__ float srow1[64];
  __shared__ float srow2[256];

  const int tid = threadIdx.x, lane = tid & 63, wv = tid >> 6;
  const int l15 = lane & 15, lg = lane >> 4;

  const bf16* qb  = q  + (size_t)b * SEQ * CH + h * 32;
  const bf16* kb  = k  + (size_t)b * SEQ * CH + h * 32;
  const bf16* vb  = v  + (size_t)b * SEQ * CH + h * 32;
  const bf16* a1b = a1 + (size_t)b * AG  * CH + h * 32;
  const bf16* a2b = a2 + (size_t)b * AG  * CH + h * 32;

  // ---- stage V^T into LDS ----
  {
    const int p = tid & 127, dg = tid >> 7;
    const bf16* s0 = vb + (size_t)(2 * p) * CH + dg * 16;
    bf16x8 r0a = ((const bf16x8*)s0)[0];
    bf16x8 r0b = ((const bf16x8*)s0)[1];
    bf16x8 r1a = ((const bf16x8*)(s0 + CH))[0];
    bf16x8 r1b = ((const bf16x8*)(s0 + CH))[1];
    #pragma unroll
    for (int j = 0; j < 8; ++j) {
      union { bf16 e[2]; unsigned u; } u0, u1;
      u0.e[0] = r0a[j]; u0.e[1] = r1a[j];
      u1.e[0] = r0b[j]; u1.e[1] = r1b[j];
      *(unsigned*)&sVT[dg * 16 + j][2 * p]     = u0.u;
      *(unsigned*)&sVT[dg * 16 + 8 + j][2 * p] = u1.u;
    }
  }

  // ---- stage-1 logits ----
  {
    bf16x8 afr[4];
    #pragma unroll
    for (int rt = 0; rt < 4; ++rt)
      afr[rt] = *(const bf16x8*)(a2b + (size_t)(16 * rt + l15) * CH + 8 * lg);
    #pragma unroll
    for (int ct = 0; ct < 4; ++ct) {
      const int n = 64 * wv + 16 * ct + l15;
      bf16x8 bfr = *(const bf16x8*)(kb + (size_t)n * CH + 8 * lg);
      #pragma unroll
      for (int rt = 0; rt < 4; ++rt) {
        f32x4 acc = {0.f, 0.f, 0.f, 0.f};
        acc = __builtin_amdgcn_mfma_f32_16x16x32_bf16(afr[rt], bfr, acc, 0, 0, 0);
        #pragma unroll
        for (int r = 0; r < 4; ++r)
          log1[16 * rt + 4 * lg + r][n] = (bf16)acc[r];
      }
    }
  }
  __syncthreads();

  // ---- softmax over n ----
  if (tid < 196) {
    const int a = tid >> 2, qu = tid & 3;
    const float* pbrow = pb + ((size_t)h * AG + a) * SEQ + qu * 64;
    float vbuf[64];
    float m = -1e30f;
    #pragma unroll
    for (int i2 = 0; i2 < 8; ++i2) {
      bf16x8 raw = *(const bf16x8*)&log1[a][qu * 64 + 8 * i2];
      #pragma unroll
      for (int j = 0; j < 8; ++j) {
        float x = QK_SCALE * (float)raw[j] + pbrow[8 * i2 + j];
        vbuf[8 * i2 + j] = x;
        m = fmaxf(m, x);
      }
    }
    m = fmaxf(m, __shfl_xor(m, 1));
    m = fmaxf(m, __shfl_xor(m, 2));
    float s = 0.f;
    #pragma unroll
    for (int i2 = 0; i2 < 8; ++i2) {
      bf16x8 eb;
      #pragma unroll
      for (int j = 0; j < 8; ++j) {
        float e = __expf(vbuf[8 * i2 + j] - m);
        s += e;
        eb[j] = (bf16)e;
      }
      *(bf16x8*)&log1[a][qu * 64 + 8 * i2] = eb;
    }
    s += __shfl_xor(s, 1);
    s += __shfl_xor(s, 2);
    if (qu == 0) srow1[a] = 1.f / s;
  }
  __syncthreads();

  // ---- PV1 ----
  {
    f32x4 acc0 = {0.f, 0.f, 0.f, 0.f}, acc1 = {0.f, 0.f, 0.f, 0.f};
    #pragma unroll
    for (int ksn = 0; ksn < 8; ++ksn) {
      bf16x8 af = *(const bf16x8*)&log1[16 * wv + l15][32 * ksn + 8 * lg];
      bf16x8 b0 = *(const bf16x8*)&sVT[l15][32 * ksn + 8 * lg];
      bf16x8 b1 = *(const bf16x8*)&sVT[16 + l15][32 * ksn + 8 * lg];
      acc0 = __builtin_amdgcn_mfma_f32_16x16x32_bf16(af, b0, acc0, 0, 0, 0);
      acc1 = __builtin_amdgcn_mfma_f32_16x16x32_bf16(af, b1, acc1, 0, 0, 0);
    }
    #pragma unroll
    for (int r = 0; r < 4; ++r) {
      const int a = 16 * wv + 4 * lg + r;
      const float inv = (a < AG) ? srow1[a] : 0.f;
      sAVT[l15][a]      = (bf16)(acc0[r] * inv);
      sAVT[16 + l15][a] = (bf16)(acc1[r] * inv);
    }
  }
  __syncthreads();

  // ---- stage-2 logits ----
  {
    bf16x8 bfr[4];
    #pragma unroll
    for (int ct = 0; ct < 4; ++ct)
      bfr[ct] = *(const bf16x8*)(a1b + (size_t)(16 * ct + l15) * CH + 8 * lg);
    #pragma unroll
    for (int rt = 0; rt < 4; ++rt) {
      bf16x8 af = *(const bf16x8*)(qb + (size_t)(64 * wv + 16 * rt + l15) * CH + 8 * lg);
      #pragma unroll
      for (int ct = 0; ct < 4; ++ct) {
        f32x4 acc = {0.f, 0.f, 0.f, 0.f};
        acc = __builtin_amdgcn_mfma_f32_16x16x32_bf16(af, bfr[ct], acc, 0, 0, 0);
        #pragma unroll
        for (int r = 0; r < 4; ++r)
          log2[64 * wv + 16 * rt + 4 * lg + r][16 * ct + l15] = (bf16)acc[r];
      }
    }
  }
  __syncthreads();

  // ---- softmax over a (49) ----
  {
    const float* abrow = ab + ((size_t)h * SEQ + tid) * AG;
    float vb2[49];
    float m = -1e30f;
    #pragma unroll
    for (int i2 = 0; i2 < 6; ++i2) {
      bf16x8 raw = *(const bf16x8*)&log2[tid][8 * i2];
      #pragma unroll
      for (int j = 0; j < 8; ++j) {
        float x = QK_SCALE * (float)raw[j] + abrow[8 * i2 + j];
        vb2[8 * i2 + j] = x;
        m = fmaxf(m, x);
      }
    }
    {
      float x = QK_SCALE * (float)log2[tid][48] + abrow[48];
      vb2[48] = x;
      m = fmaxf(m, x);
    }
    float s = 0.f;
    #pragma unroll
    for (int i2 = 0; i2 < 8; ++i2) {
      bf16x8 eb;
      #pragma unroll
      for (int j = 0; j < 8; ++j) {
        const int idx = 8 * i2 + j;
        float e = 0.f;
        if (idx < AG) { e = __expf(vb2[idx] - m); }
        s += e;
        eb[j] = (bf16)e;
      }
      *(bf16x8*)&log2[tid][8 * i2] = eb;
    }
    srow2[tid] = 1.f / s;
  }
  __syncthreads();

  // ---- PV2 ----
  {
    bf16x8 bfr[2][2];
    #pragma unroll
    for (int ksn = 0; ksn < 2; ++ksn) {
      bfr[ksn][0] = *(const bf16x8*)&sAVT[l15][32 * ksn + 8 * lg];
      bfr[ksn][1] = *(const bf16x8*)&sAVT[16 + l15][32 * ksn + 8 * lg];
    }
    bf16* outp = xout + (size_t)b * SEQ * CH + h * 32;
    #pragma unroll
    for (int rt = 0; rt < 4; ++rt) {
      f32x4 acc0 = {0.f, 0.f, 0.f, 0.f}, acc1 = {0.f, 0.f, 0.f, 0.f};
      #pragma unroll
      for (int ksn = 0; ksn < 2; ++ksn) {
        bf16x8 af = *(const bf16x8*)&log2[64 * wv + 16 * rt + l15][32 * ksn + 8 * lg];
        acc0 = __builtin_amdgcn_mfma_f32_16x16x32_bf16(af, bfr[ksn][0], acc0, 0, 0, 0);
        acc1 = __builtin_amdgcn_mfma_f32_16x16x32_bf16(af, bfr[ksn][1], acc1, 0, 0, 0);
      }
      #pragma unroll
      for (int r = 0; r < 4; ++r) {
        const int nq = 64 * wv + 16 * rt + 4 * lg + r;
        const float inv = srow2[nq];
        outp[(size_t)nq * CH + l15]      = (bf16)(acc0[r] * inv);
        outp[(size_t)nq * CH + 16 + l15] = (bf16)(acc1[r] * inv);
      }
    }
  }
}

// ---------------------------------------------------------------------------
// K6: xsum = x_attn + depthwise3x3(q) + dwc_b
DEVI void fma8(float* acc, bf16x8 qv, float4 wa, float4 wb) {
  acc[0] += (float)qv[0] * wa.x; acc[1] += (float)qv[1] * wa.y;
  acc[2] += (float)qv[2] * wa.z; acc[3] += (float)qv[3] * wa.w;
  acc[4] += (float)qv[4] * wb.x; acc[5] += (float)qv[5] * wb.y;
  acc[6] += (float)qv[6] * wb.z; acc[7] += (float)qv[7] * wb.w;
}

__global__ __launch_bounds__(256) void k_dwconv(
    const bf16* q, const bf16* xattn, const float* dwc_w, const float* dwc_b,
    bf16* xsum) {
  __shared__ bf16 sQ[144][200] __attribute__((aligned(16)));
  __shared__ float sW[9][192] __attribute__((aligned(16)));
  const int half = blockIdx.x, b = blockIdx.y;
  const int t = threadIdx.x;
  const int base_n = half ? 112 : 0;

  if (t < 144) {
    const bf16* qs = q + ((size_t)b * SEQ + base_n + t) * CH;
    #pragma unroll
    for (int i2 = 0; i2 < 24; ++i2)
      *(uint4*)&sQ[t][8 * i2] = ((const uint4*)qs)[i2];
  }
  for (int idx = t; idx < 9 * 192; idx += 256) {
    int cc = idx / 9, tap = idx - cc * 9;
    sW[tap][cc] = dwc_w[idx];
  }
  __syncthreads();

  const int nloc = t & 127, chalf = t >> 7;
  const int n = half * 128 + nloc;
  const int ii = n >> 4, jj = n & 15;
  const bf16* xa = xattn + ((size_t)b * SEQ + n) * CH;
  bf16* xo = xsum + ((size_t)b * SEQ + n) * CH;
  const int c_base = chalf * 96;

  for (int c0 = c_base; c0 < c_base + 96; c0 += 8) {
    float accv[8];
    {
      const float4* bsrc = (const float4*)(dwc_b + c0);
      float4 b0 = bsrc[0], b1 = bsrc[1];
      accv[0] = b0.x; accv[1] = b0.y; accv[2] = b0.z; accv[3] = b0.w;
      accv[4] = b1.x; accv[5] = b1.y; accv[6] = b1.z; accv[7] = b1.w;
    }
    {
      bf16x8 xv = *(const bf16x8*)(xa + c0);
      #pragma unroll
      for (int j = 0; j < 8; ++j) accv[j] += (float)xv[j];
    }
    #pragma unroll
    for (int di = 0; di < 3; ++di) {
      const int i2 = ii + di - 1;
      if ((unsigned)i2 >= 16u) continue;
      #pragma unroll
      for (int dj = 0; dj < 3; ++dj) {
        const int j2 = jj + dj - 1;
        if ((unsigned)j2 >= 16u) continue;
        const int nn = i2 * 16 + j2 - base_n;
        bf16x8 qv = *(const bf16x8*)&sQ[nn][c0];
        const float4* wv4 = (const float4*)&sW[di * 3 + dj][c0];
        fma8(accv, qv, wv4[0], wv4[1]);
      }
    }
    bf16x8 ob;
    #pragma unroll
    for (int j = 0; j < 8; ++j) ob[j] = (bf16)accv[j];
    *(bf16x8*)(xo + c0) = ob;
  }
}

// ---------------------------------------------------------------------------
extern "C" void kernel_launch(void* const* d_in, const int* in_sizes, int n_in,
                              void* d_out, int out_size, void* d_ws, size_t ws_size,
                              hipStream_t stream) {
  (void)in_sizes; (void)n_in; (void)out_size; (void)ws_size;
  const float* xF1 = (const float*)d_in[0];
  const float* xC2 = (const float*)d_in[1];
  const float* xC1 = (const float*)d_in[2];
  const float* Wq  = (const float*)d_in[3];
  const float* bq  = (const float*)d_in[4];
  const float* Wk  = (const float*)d_in[5];
  const float* bk  = (const float*)d_in[6];
  const float* Wv  = (const float*)d_in[7];
  const float* bv  = (const float*)d_in[8];
  const float* Wa1 = (const float*)d_in[9];
  const float* ba1 = (const float*)d_in[10];
  const float* Wa2 = (const float*)d_in[11];
  const float* ba2 = (const float*)d_in[12];
  const float* an_bias = (const float*)d_in[13];
  const float* na_bias = (const float*)d_in[14];
  const float* ah_bias = (const float*)d_in[15];
  const float* aw_bias = (const float*)d_in[16];
  const float* ha_bias = (const float*)d_in[17];
  const float* wa_bias = (const float*)d_in[18];
  const float* dwc_w = (const float*)d_in[19];
  const float* dwc_b = (const float*)d_in[20];
  const float* Wp  = (const float*)d_in[21];
  const float* bp  = (const float*)d_in[22];

  char* ws = (char*)d_ws;
  size_t off = 0;
  auto nxt = [&](size_t bytes) -> char* {
    char* p = ws + off;
    off = (off + bytes + 255) & ~(size_t)255;
    return p;
  };
  const size_t XSZ = (size_t)BATCH * SEQ * CH;
  const size_t ASZ = ((size_t)BATCH * AG + 64) * CH;

  bf16*  wsW     = (bf16*)nxt(6 * 36864 * sizeof(bf16));
  float* pb      = (float*)nxt(6 * 49 * 256 * sizeof(float));
  float* ab      = (float*)nxt(6 * 256 * 49 * sizeof(float));
  bf16*  pooled1 = (bf16*)nxt(ASZ * sizeof(bf16));
  bf16*  pooled2 = (bf16*)nxt(ASZ * sizeof(bf16));
  bf16*  qB      = (bf16*)nxt(XSZ * sizeof(bf16));
  bf16*  kB      = (bf16*)nxt(XSZ * sizeof(bf16));
  bf16*  vB      = (bf16*)nxt(XSZ * sizeof(bf16));
  bf16*  a1B     = (bf16*)nxt(ASZ * sizeof(bf16));
  bf16*  a2B     = (bf16*)nxt(ASZ * sizeof(bf16));
  bf16*  xattn   = (bf16*)nxt(XSZ * sizeof(bf16));
  bf16*  xsum    = (bf16*)nxt(XSZ * sizeof(bf16));

  k_prep<<<1548, 256, 0, stream>>>(Wq, Wk, Wv, Wa1, Wa2, Wp,
                                   an_bias, na_bias, ah_bias, aw_bias,
                                   ha_bias, wa_bias, wsW, pb, ab, a1B, a2B);
  k_pool<<<dim3(BATCH, 2), 192, 0, stream>>>(xC1, xC2, pooled1, pooled2);
  k_gemm2<<<dim3(98, 2), 256, 0, stream>>>(pooled1, pooled2, wsW, ba1, ba2, a1B, a2B);
  k_gemm3<<<2048, 256, 0, stream>>>(xF1, xC2, xC1, wsW, bq, bk, bv, qB, kB, vB);
  k_attn<<<dim3(NH, BATCH), 256, 0, stream>>>(qB, kB, vB, a1B, a2B, pb, ab, xattn);
  k_dwconv<<<dim3(2, BATCH), 256, 0, stream>>>(qB, xattn, dwc_w, dwc_b, xsum);
  k_gemm_out<<<2048, 256, 0, stream>>>(xsum, wsW + 5 * 36864, bp, (float*)d_out);
}

// Round 4
// 248.626 us; speedup vs baseline: 1.2550x; 1.2550x over previous
//
#include <hip/hip_runtime.h>

typedef __bf16 bf16;
typedef __bf16 bf16x8 __attribute__((ext_vector_type(8)));
typedef float  f32x4  __attribute__((ext_vector_type(4)));

#define DEVI __device__ __forceinline__

static constexpr int   BATCH = 256;
static constexpr int   SEQ   = 256;
static constexpr int   CH    = 192;
static constexpr int   NH    = 6;
static constexpr int   AG    = 49;
static constexpr float QK_SCALE = 0.17677669529663687f;  // 32^-0.5

// ---- adaptive-avg-pool 16 -> 7: inverse bin tables ----
__device__ constexpr int   PPN[16]  = {1,1,2,1,2,1,2,1,1,2,1,2,1,2,1,1};
__device__ constexpr int   PPB0[16] = {0,0,0,1,1,2,2,3,3,3,4,4,5,5,6,6};
__device__ constexpr int   PPB1[16] = {0,0,1,0,2,0,3,0,0,4,0,5,0,6,0,0};
__device__ constexpr float PPW0[16] = {1.f/3.f,1.f/3.f,1.f/3.f,1.f/3.f,1.f/3.f,1.f/3.f,1.f/3.f,0.25f,0.25f,0.25f,
                                       1.f/3.f,1.f/3.f,1.f/3.f,1.f/3.f,1.f/3.f,1.f/3.f};
__device__ constexpr float PPW1[16] = {0.f,0.f,1.f/3.f,0.f,1.f/3.f,0.f,0.25f,0.f,0.f,1.f/3.f,
                                       0.f,1.f/3.f,0.f,1.f/3.f,0.f,0.f};

// ---------------------------------------------------------------------------
#if defined(__has_builtin)
#if __has_builtin(__builtin_amdgcn_global_load_lds)
#define HAVE_GLL 1
#endif
#endif

// async global->LDS 16B: g is PER-LANE source, l is wave-uniform LDS base
// (HW writes l + lane*16).
DEVI void gll16(const void* g, void* l, int lane) {
#ifdef HAVE_GLL
  (void)lane;
  __builtin_amdgcn_global_load_lds(
      (const __attribute__((address_space(1))) void*)g,
      (__attribute__((address_space(3))) void*)l, 16, 0, 0);
#else
  *(uint4*)((char*)l + lane * 16) = *(const uint4*)((const char*)g);
#endif
}

// ---------------------------------------------------------------------------
DEVI float bilin7(const float* m, int i, int j) {
  float sh = (i + 0.5f) * 0.4375f - 0.5f; sh = sh < 0.f ? 0.f : sh;
  float sw = (j + 0.5f) * 0.4375f - 0.5f; sw = sw < 0.f ? 0.f : sw;
  int i0 = (int)sh; if (i0 > 6) i0 = 6;
  int j0 = (int)sw; if (j0 > 6) j0 = 6;
  int i1 = i0 + 1;  if (i1 > 6) i1 = 6;
  int j1 = j0 + 1;  if (j1 > 6) j1 = 6;
  float th = sh - (float)i0, tw = sw - (float)j0;
  float v00 = m[i0*7 + j0], v01 = m[i0*7 + j1];
  float v10 = m[i1*7 + j0], v11 = m[i1*7 + j1];
  return (v00*(1.f-tw) + v01*tw)*(1.f-th) + (v10*(1.f-tw) + v11*tw)*th;
}

// ---------------------------------------------------------------------------
// K1: weights->bf16, pb[h][a][n], ab[h][n][a], zero pads of a1/a2
__global__ void k_prep(const float* Wq, const float* Wk, const float* Wv,
                       const float* Wa1, const float* Wa2, const float* Wp,
                       const float* an_bias, const float* na_bias,
                       const float* ah_bias, const float* aw_bias,
                       const float* ha_bias, const float* wa_bias,
                       bf16* wsW, float* pb, float* ab, bf16* a1, bf16* a2) {
  int gid = blockIdx.x * 256 + threadIdx.x;
  if (gid < 221184) {
    int mi = gid / 36864, r = gid - mi * 36864;
    const float* W = (mi == 0 ? Wq : mi == 1 ? Wk : mi == 2 ? Wv :
                      mi == 3 ? Wa1 : mi == 4 ? Wa2 : Wp);
    wsW[gid] = (bf16)W[r];
  } else if (gid < 296448) {                // pb: [h][49][256]
    int r = gid - 221184;
    int n = r & 255, ha = r >> 8;
    int i = n >> 4, j = n & 15;
    float val = bilin7(an_bias + (size_t)ha * 49, i, j)
              + ah_bias[ha * 16 + i] + aw_bias[ha * 16 + j];
    pb[r] = val;
  } else if (gid < 371712) {                // ab: [h][256][49]
    int r = gid - 296448;
    int a = r % 49, hn = r / 49;
    int n = hn & 255, hh = hn >> 8;
    int i = n >> 4, j = n & 15;
    float val = bilin7(na_bias + (size_t)(hh * 49 + a) * 49, i, j)
              + ha_bias[(hh * 16 + i) * 49 + a] + wa_bias[(hh * 16 + j) * 49 + a];
    ab[r] = val;
  } else if (gid < 396288) {                // zero 64 pad rows of a1,a2
    int r = gid - 371712;
    if (r < 12288) a1[(size_t)12544 * CH + r] = (bf16)0.f;
    else           a2[(size_t)12544 * CH + (r - 12288)] = (bf16)0.f;
  }
}

// ---------------------------------------------------------------------------
// K2: streaming combos fp32 -> bf16, XOR-swizzled 16B-chunk layout:
//   out[row][byte (cb*16)^((row&7)<<4)] = chunk cb of row.
// Consumed only by gload_lds GEMMs (which read with the same XOR).
__global__ __launch_bounds__(256) void k_combo(
    const float* xF1, const float* xC2, const float* xC1,
    bf16* f1b, bf16* kin, bf16* vin) {
  const int base = blockIdx.x * 768;           // 32 rows * 24 chunks
  #pragma unroll
  for (int s = 0; s < 3; ++s) {
    const int slot = base + threadIdx.x + 256 * s;
    const int row  = slot / 24;
    const int cb   = slot - row * 24;
    const size_t rf = (size_t)row * CH + cb * 8;
    float f[8], c2[8], c1[8];
    *(float4*)&f[0]  = *(const float4*)(xF1 + rf);
    *(float4*)&f[4]  = *(const float4*)(xF1 + rf + 4);
    *(float4*)&c2[0] = *(const float4*)(xC2 + rf);
    *(float4*)&c2[4] = *(const float4*)(xC2 + rf + 4);
    *(float4*)&c1[0] = *(const float4*)(xC1 + rf);
    *(float4*)&c1[4] = *(const float4*)(xC1 + rf + 4);
    bf16x8 tq, tk, tv;
    #pragma unroll
    for (int e = 0; e < 8; ++e) {
      const float d = c2[e] - c1[e];
      tq[e] = (bf16)f[e];
      tk[e] = (bf16)(f[e] + d);
      tv[e] = (bf16)d;
    }
    const size_t rowb = (size_t)row * 384;
    const int    byt  = (cb * 16) ^ ((row & 7) << 4);
    *(bf16x8*)((char*)f1b + rowb + byt) = tq;
    *(bf16x8*)((char*)kin + rowb + byt) = tk;
    *(bf16x8*)((char*)vin + rowb + byt) = tv;
  }
}

// ---------------------------------------------------------------------------
// K3: adaptive 16x16 -> 7x7 avg pool (r2 proven: fully static indexing).
__global__ __launch_bounds__(192) void k_pool(
    const float* xC1, const float* xC2, bf16* pooled1, bf16* pooled2) {
  const int b = blockIdx.x, which = blockIdx.y, c = threadIdx.x;
  const float* src = (which ? xC2 : xC1) + (size_t)b * SEQ * CH + c;
  bf16* dst = (which ? pooled2 : pooled1) + (size_t)b * AG * CH + c;
  float acc[49];
  #pragma unroll
  for (int a = 0; a < 49; ++a) acc[a] = 0.f;
  #pragma unroll
  for (int i = 0; i < 16; ++i) {
    float jq[7] = {0.f, 0.f, 0.f, 0.f, 0.f, 0.f, 0.f};
    #pragma unroll
    for (int j = 0; j < 16; ++j) {
      const float x = src[(i * 16 + j) * CH];
      jq[PPB0[j]] += PPW0[j] * x;
      if (PPN[j] == 2) jq[PPB1[j]] += PPW1[j] * x;
    }
    {
      const int p0 = PPB0[i]; const float w0 = PPW0[i];
      #pragma unroll
      for (int qq = 0; qq < 7; ++qq) acc[p0 * 7 + qq] += w0 * jq[qq];
    }
    if (PPN[i] == 2) {
      const int p1 = PPB1[i]; const float w1 = PPW1[i];
      #pragma unroll
      for (int qq = 0; qq < 7; ++qq) acc[p1 * 7 + qq] += w1 * jq[qq];
    }
  }
  #pragma unroll
  for (int a = 0; a < 49; ++a) dst[(size_t)a * CH + c] = (bf16)acc[a];
}

// ---------------------------------------------------------------------------
// K4: q/k/v GEMM from pre-swizzled bf16 inputs via global_load_lds.
// grid (512 tiles, 3 jobs), 256 thr = 4 waves (2x2 over 128 rows x 192 cols).
__global__ __launch_bounds__(256, 3) void k_gemm3b(
    const bf16* f1b, const bf16* kin, const bf16* vin, const bf16* wsW,
    const float* bq, const float* bk, const float* bv,
    bf16* qO, bf16* kO, bf16* vO) {
  __shared__ char sA[49152] __attribute__((aligned(16)));
  const int tid = threadIdx.x, lane = tid & 63, wid = tid >> 6;
  const int l15 = lane & 15, lg = lane >> 4;
  const int wr = wid >> 1, wc = wid & 1;
  const int job = blockIdx.y;
  const int m0 = blockIdx.x * 128;
  const bf16*  Aj   = (job == 0 ? f1b : job == 1 ? kin : vin);
  const bf16*  Wj   = wsW + job * 36864;
  const float* bias = (job == 0 ? bq : job == 1 ? bk : bv);
  bf16*        outp = (job == 0 ? qO : job == 1 ? kO : vO);

  // ---- stage 48KB tile: 12 x 1KB async per wave, linear (src pre-swizzled) ----
  {
    const char* gsrc = (const char*)Aj + (size_t)m0 * 384;
    #pragma unroll
    for (int i = 0; i < 12; ++i) {
      const int off = (wid * 12 + i) * 1024;
      gll16(gsrc + off + lane * 16, sA + off, lane);
    }
  }
  __syncthreads();

  f32x4 acc[4][6];
  #pragma unroll
  for (int a = 0; a < 4; ++a)
    #pragma unroll
    for (int b2 = 0; b2 < 6; ++b2) acc[a][b2] = f32x4{0.f, 0.f, 0.f, 0.f};

  #pragma unroll
  for (int kk = 0; kk < 6; ++kk) {
    bf16x8 af[4];
    #pragma unroll
    for (int rt = 0; rt < 4; ++rt) {
      const int row = 64 * wr + 16 * rt + l15;
      af[rt] = *(const bf16x8*)(sA + row * 384 + ((kk * 64 + lg * 16) ^ ((row & 7) << 4)));
    }
    #pragma unroll
    for (int ct = 0; ct < 6; ++ct) {
      const int ncol = 96 * wc + 16 * ct + l15;
      bf16x8 bfr = *(const bf16x8*)&Wj[(size_t)ncol * CH + kk * 32 + 8 * lg];
      #pragma unroll
      for (int rt = 0; rt < 4; ++rt)
        acc[rt][ct] = __builtin_amdgcn_mfma_f32_16x16x32_bf16(af[rt], bfr, acc[rt][ct], 0, 0, 0);
    }
  }
  __syncthreads();   // sA dead -> reuse as swizzled output restage
  #pragma unroll
  for (int ct = 0; ct < 6; ++ct) {
    const int col = 96 * wc + 16 * ct + l15;
    const float bb = bias[col];
    #pragma unroll
    for (int rt = 0; rt < 4; ++rt)
      #pragma unroll
      for (int r = 0; r < 4; ++r) {
        const int row = 64 * wr + 16 * rt + 4 * lg + r;
        *(bf16*)(sA + row * 384 + ((2 * col) ^ ((row & 7) << 4))) = (bf16)(acc[rt][ct][r] + bb);
      }
  }
  __syncthreads();
  // ---- contiguous store: each instruction writes 1KB/wave, output LINEAR ----
  #pragma unroll
  for (int g = 0; g < 12; ++g) {
    const int ch  = tid + 256 * g;           // 3072 chunks = 128 rows x 24
    const int row = ch / 24;
    const int y   = (ch - row * 24) * 16;
    bf16x8 vv = *(const bf16x8*)(sA + row * 384 + (y ^ ((row & 7) << 4)));
    *(bf16x8*)((char*)outp + (size_t)(m0 + row) * 384 + y) = vv;
  }
}

// ---------------------------------------------------------------------------
// gemm body for a1/a2 (small, linear inputs, reg staging): tile 128x192
DEVI void gemm_body(const bf16* Asrc, const bf16* W, const float* bias,
                    bf16* outp, int m0, bf16 (*sA)[72]) {
  const int tid = threadIdx.x, lane = tid & 63, wid = tid >> 6;
  const int l15 = lane & 15, lg = lane >> 4;
  const int wr = wid >> 1, wc = wid & 1;
  const int srow = tid >> 1, shalf = tid & 1;

  f32x4 acc[4][6];
  #pragma unroll
  for (int a = 0; a < 4; ++a)
    #pragma unroll
    for (int b2 = 0; b2 < 6; ++b2) acc[a][b2] = f32x4{0.f, 0.f, 0.f, 0.f};

  for (int ks = 0; ks < 3; ++ks) {
    const int k0 = ks * 64;
    const uint4* src = (const uint4*)(Asrc + (size_t)(m0 + srow) * CH + k0 + shalf * 32);
    #pragma unroll
    for (int i2 = 0; i2 < 4; ++i2)
      *(uint4*)&sA[srow][shalf * 32 + 8 * i2] = src[i2];
    __syncthreads();
    #pragma unroll
    for (int kk = 0; kk < 64; kk += 32) {
      bf16x8 af[4];
      #pragma unroll
      for (int rt = 0; rt < 4; ++rt)
        af[rt] = *(const bf16x8*)&sA[64 * wr + 16 * rt + l15][kk + 8 * lg];
      #pragma unroll
      for (int ct = 0; ct < 6; ++ct) {
        const int ncol = 96 * wc + 16 * ct + l15;
        bf16x8 bfr = *(const bf16x8*)&W[(size_t)ncol * CH + k0 + kk + 8 * lg];
        #pragma unroll
        for (int rt = 0; rt < 4; ++rt)
          acc[rt][ct] = __builtin_amdgcn_mfma_f32_16x16x32_bf16(af[rt], bfr, acc[rt][ct], 0, 0, 0);
      }
    }
    __syncthreads();
  }
  #pragma unroll
  for (int ct = 0; ct < 6; ++ct) {
    const int col = 96 * wc + 16 * ct + l15;
    const float bb = bias[col];
    #pragma unroll
    for (int rt = 0; rt < 4; ++rt) {
      const size_t rbase = (size_t)(m0 + 64 * wr + 16 * rt + 4 * lg);
      #pragma unroll
      for (int r = 0; r < 4; ++r)
        outp[(rbase + r) * CH + col] = (bf16)(acc[rt][ct][r] + bb);
    }
  }
}

// K5: a1/a2 projections
__global__ __launch_bounds__(256, 2) void k_gemm2(
    const bf16* pooled1, const bf16* pooled2, const bf16* wsW,
    const float* ba1, const float* ba2, bf16* a1, bf16* a2) {
  __shared__ bf16 sA[128][72] __attribute__((aligned(16)));
  const int m0 = blockIdx.x * 128;
  if (blockIdx.y == 0) gemm_body(pooled1, wsW + 3 * 36864, ba1, a1, m0, sA);
  else                 gemm_body(pooled2, wsW + 4 * 36864, ba2, a2, m0, sA);
}

// ---------------------------------------------------------------------------
// K8: output projection from pre-swizzled xsum via gload_lds; fp32 direct store.
__global__ __launch_bounds__(256, 3) void k_gemm_out(
    const bf16* xsum, const bf16* Wp, const float* bp, float* out) {
  __shared__ char sA[49152] __attribute__((aligned(16)));
  const int tid = threadIdx.x, lane = tid & 63, wid = tid >> 6;
  const int l15 = lane & 15, lg = lane >> 4;
  const int wr = wid >> 1, wc = wid & 1;
  const int m0 = blockIdx.x * 128;

  {
    const char* gsrc = (const char*)xsum + (size_t)m0 * 384;
    #pragma unroll
    for (int i = 0; i < 12; ++i) {
      const int off = (wid * 12 + i) * 1024;
      gll16(gsrc + off + lane * 16, sA + off, lane);
    }
  }
  __syncthreads();

  f32x4 acc[4][6];
  #pragma unroll
  for (int a = 0; a < 4; ++a)
    #pragma unroll
    for (int b2 = 0; b2 < 6; ++b2) acc[a][b2] = f32x4{0.f, 0.f, 0.f, 0.f};

  #pragma unroll
  for (int kk = 0; kk < 6; ++kk) {
    bf16x8 af[4];
    #pragma unroll
    for (int rt = 0; rt < 4; ++rt) {
      const int row = 64 * wr + 16 * rt + l15;
      af[rt] = *(const bf16x8*)(sA + row * 384 + ((kk * 64 + lg * 16) ^ ((row & 7) << 4)));
    }
    #pragma unroll
    for (int ct = 0; ct < 6; ++ct) {
      const int ncol = 96 * wc + 16 * ct + l15;
      bf16x8 bfr = *(const bf16x8*)&Wp[(size_t)ncol * CH + kk * 32 + 8 * lg];
      #pragma unroll
      for (int rt = 0; rt < 4; ++rt)
        acc[rt][ct] = __builtin_amdgcn_mfma_f32_16x16x32_bf16(af[rt], bfr, acc[rt][ct], 0, 0, 0);
    }
  }
  // fp32 scatter store: each quarter-wave writes a full 64B sector
  #pragma unroll
  for (int ct = 0; ct < 6; ++ct) {
    const int col = 96 * wc + 16 * ct + l15;
    const float bb = bp[col];
    #pragma unroll
    for (int rt = 0; rt < 4; ++rt)
      #pragma unroll
      for (int r = 0; r < 4; ++r)
        out[(size_t)(m0 + 64 * wr + 16 * rt + 4 * lg + r) * CH + col] = acc[rt][ct][r] + bb;
  }
}

// ---------------------------------------------------------------------------
// K6: fused two-stage agent attention per (b, h). 256 threads = 4 waves.
__global__ __launch_bounds__(256, 2) void k_attn(
    const bf16* q, const bf16* k, const bf16* v,
    const bf16* a1, const bf16* a2, const float* pb, const float* ab,
    bf16* xout) {
  const int h = blockIdx.x, b = blockIdx.y;
  __shared__ char uSmem[36864] __attribute__((aligned(16)));   // log1[64][264] | log2[256][72]
  bf16 (*log1)[264] = reinterpret_cast<bf16 (*)[264]>(uSmem);
  bf16 (*log2)[72]  = reinterpret_cast<bf16 (*)[72]>(uSmem);
  __shared__ bf16 sVT[32][264] __attribute__((aligned(16)));
  __shared__ bf16 sAVT[32][72] __attribute__((aligned(16)));
  __shared__ float srow1[64];
  __shared__ float srow2[256];

  const int tid = threadIdx.x, lane = tid & 63, wv = tid >> 6;
  const int l15 = lane & 15, lg = lane >> 4;

  const bf16* qb  = q  + (size_t)b * SEQ * CH + h * 32;
  const bf16* kb  = k  + (size_t)b * SEQ * CH + h * 32;
  const bf16* vb  = v  + (size_t)b * SEQ * CH + h * 32;
  const bf16* a1b = a1 + (size_t)b * AG  * CH + h * 32;
  const bf16* a2b = a2 + (size_t)b * AG  * CH + h * 32;

  // ---- stage V^T into LDS ----
  {
    const int p = tid & 127, dg = tid >> 7;
    const bf16* s0 = vb + (size_t)(2 * p) * CH + dg * 16;
    bf16x8 r0a = ((const bf16x8*)s0)[0];
    bf16x8 r0b = ((const bf16x8*)s0)[1];
    bf16x8 r1a = ((const bf16x8*)(s0 + CH))[0];
    bf16x8 r1b = ((const bf16x8*)(s0 + CH))[1];
    #pragma unroll
    for (int j = 0; j < 8; ++j) {
      union { bf16 e[2]; unsigned u; } u0, u1;
      u0.e[0] = r0a[j]; u0.e[1] = r1a[j];
      u1.e[0] = r0b[j]; u1.e[1] = r1b[j];
      *(unsigned*)&sVT[dg * 16 + j][2 * p]     = u0.u;
      *(unsigned*)&sVT[dg * 16 + 8 + j][2 * p] = u1.u;
    }
  }

  // ---- stage-1 logits ----
  {
    bf16x8 afr[4];
    #pragma unroll
    for (int rt = 0; rt < 4; ++rt)
      afr[rt] = *(const bf16x8*)(a2b + (size_t)(16 * rt + l15) * CH + 8 * lg);
    #pragma unroll
    for (int ct = 0; ct < 4; ++ct) {
      const int n = 64 * wv + 16 * ct + l15;
      bf16x8 bfr = *(const bf16x8*)(kb + (size_t)n * CH + 8 * lg);
      #pragma unroll
      for (int rt = 0; rt < 4; ++rt) {
        f32x4 acc = {0.f, 0.f, 0.f, 0.f};
        acc = __builtin_amdgcn_mfma_f32_16x16x32_bf16(afr[rt], bfr, acc, 0, 0, 0);
        #pragma unroll
        for (int r = 0; r < 4; ++r)
          log1[16 * rt + 4 * lg + r][n] = (bf16)acc[r];
      }
    }
  }
  __syncthreads();

  // ---- softmax over n ----
  if (tid < 196) {
    const int a = tid >> 2, qu = tid & 3;
    const float* pbrow = pb + ((size_t)h * AG + a) * SEQ + qu * 64;
    float vbuf[64];
    float m = -1e30f;
    #pragma unroll
    for (int i2 = 0; i2 < 8; ++i2) {
      bf16x8 raw = *(const bf16x8*)&log1[a][qu * 64 + 8 * i2];
      #pragma unroll
      for (int j = 0; j < 8; ++j) {
        float x = QK_SCALE * (float)raw[j] + pbrow[8 * i2 + j];
        vbuf[8 * i2 + j] = x;
        m = fmaxf(m, x);
      }
    }
    m = fmaxf(m, __shfl_xor(m, 1));
    m = fmaxf(m, __shfl_xor(m, 2));
    float s = 0.f;
    #pragma unroll
    for (int i2 = 0; i2 < 8; ++i2) {
      bf16x8 eb;
      #pragma unroll
      for (int j = 0; j < 8; ++j) {
        float e = __expf(vbuf[8 * i2 + j] - m);
        s += e;
        eb[j] = (bf16)e;
      }
      *(bf16x8*)&log1[a][qu * 64 + 8 * i2] = eb;
    }
    s += __shfl_xor(s, 1);
    s += __shfl_xor(s, 2);
    if (qu == 0) srow1[a] = 1.f / s;
  }
  __syncthreads();

  // ---- PV1 ----
  {
    f32x4 acc0 = {0.f, 0.f, 0.f, 0.f}, acc1 = {0.f, 0.f, 0.f, 0.f};
    #pragma unroll
    for (int ksn = 0; ksn < 8; ++ksn) {
      bf16x8 af = *(const bf16x8*)&log1[16 * wv + l15][32 * ksn + 8 * lg];
      bf16x8 b0 = *(const bf16x8*)&sVT[l15][32 * ksn + 8 * lg];
      bf16x8 b1 = *(const bf16x8*)&sVT[16 + l15][32 * ksn + 8 * lg];
      acc0 = __builtin_amdgcn_mfma_f32_16x16x32_bf16(af, b0, acc0, 0, 0, 0);
      acc1 = __builtin_amdgcn_mfma_f32_16x16x32_bf16(af, b1, acc1, 0, 0, 0);
    }
    #pragma unroll
    for (int r = 0; r < 4; ++r) {
      const int a = 16 * wv + 4 * lg + r;
      const float inv = (a < AG) ? srow1[a] : 0.f;
      sAVT[l15][a]      = (bf16)(acc0[r] * inv);
      sAVT[16 + l15][a] = (bf16)(acc1[r] * inv);
    }
  }
  __syncthreads();

  // ---- stage-2 logits ----
  {
    bf16x8 bfr[4];
    #pragma unroll
    for (int ct = 0; ct < 4; ++ct)
      bfr[ct] = *(const bf16x8*)(a1b + (size_t)(16 * ct + l15) * CH + 8 * lg);
    #pragma unroll
    for (int rt = 0; rt < 4; ++rt) {
      bf16x8 af = *(const bf16x8*)(qb + (size_t)(64 * wv + 16 * rt + l15) * CH + 8 * lg);
      #pragma unroll
      for (int ct = 0; ct < 4; ++ct) {
        f32x4 acc = {0.f, 0.f, 0.f, 0.f};
        acc = __builtin_amdgcn_mfma_f32_16x16x32_bf16(af, bfr[ct], acc, 0, 0, 0);
        #pragma unroll
        for (int r = 0; r < 4; ++r)
          log2[64 * wv + 16 * rt + 4 * lg + r][16 * ct + l15] = (bf16)acc[r];
      }
    }
  }
  __syncthreads();

  // ---- softmax over a (49) ----
  {
    const float* abrow = ab + ((size_t)h * SEQ + tid) * AG;
    float vb2[49];
    float m = -1e30f;
    #pragma unroll
    for (int i2 = 0; i2 < 6; ++i2) {
      bf16x8 raw = *(const bf16x8*)&log2[tid][8 * i2];
      #pragma unroll
      for (int j = 0; j < 8; ++j) {
        float x = QK_SCALE * (float)raw[j] + abrow[8 * i2 + j];
        vb2[8 * i2 + j] = x;
        m = fmaxf(m, x);
      }
    }
    {
      float x = QK_SCALE * (float)log2[tid][48] + abrow[48];
      vb2[48] = x;
      m = fmaxf(m, x);
    }
    float s = 0.f;
    #pragma unroll
    for (int i2 = 0; i2 < 8; ++i2) {
      bf16x8 eb;
      #pragma unroll
      for (int j = 0; j < 8; ++j) {
        const int idx = 8 * i2 + j;
        float e = 0.f;
        if (idx < AG) { e = __expf(vb2[idx] - m); }
        s += e;
        eb[j] = (bf16)e;
      }
      *(bf16x8*)&log2[tid][8 * i2] = eb;
    }
    srow2[tid] = 1.f / s;
  }
  __syncthreads();

  // ---- PV2 ----
  {
    bf16x8 bfr[2][2];
    #pragma unroll
    for (int ksn = 0; ksn < 2; ++ksn) {
      bfr[ksn][0] = *(const bf16x8*)&sAVT[l15][32 * ksn + 8 * lg];
      bfr[ksn][1] = *(const bf16x8*)&sAVT[16 + l15][32 * ksn + 8 * lg];
    }
    bf16* outp = xout + (size_t)b * SEQ * CH + h * 32;
    #pragma unroll
    for (int rt = 0; rt < 4; ++rt) {
      f32x4 acc0 = {0.f, 0.f, 0.f, 0.f}, acc1 = {0.f, 0.f, 0.f, 0.f};
      #pragma unroll
      for (int ksn = 0; ksn < 2; ++ksn) {
        bf16x8 af = *(const bf16x8*)&log2[64 * wv + 16 * rt + l15][32 * ksn + 8 * lg];
        acc0 = __builtin_amdgcn_mfma_f32_16x16x32_bf16(af, bfr[ksn][0], acc0, 0, 0, 0);
        acc1 = __builtin_amdgcn_mfma_f32_16x16x32_bf16(af, bfr[ksn][1], acc1, 0, 0, 0);
      }
      #pragma unroll
      for (int r = 0; r < 4; ++r) {
        const int nq = 64 * wv + 16 * rt + 4 * lg + r;
        const float inv = srow2[nq];
        outp[(size_t)nq * CH + l15]      = (bf16)(acc0[r] * inv);
        outp[(size_t)nq * CH + 16 + l15] = (bf16)(acc1[r] * inv);
      }
    }
  }
}

// ---------------------------------------------------------------------------
// K7: xsum = x_attn + depthwise3x3(q) + dwc_b ; stores xsum SWIZZLED
DEVI void fma8(float* acc, bf16x8 qv, float4 wa, float4 wb) {
  acc[0] += (float)qv[0] * wa.x; acc[1] += (float)qv[1] * wa.y;
  acc[2] += (float)qv[2] * wa.z; acc[3] += (float)qv[3] * wa.w;
  acc[4] += (float)qv[4] * wb.x; acc[5] += (float)qv[5] * wb.y;
  acc[6] += (float)qv[6] * wb.z; acc[7] += (float)qv[7] * wb.w;
}

__global__ __launch_bounds__(256) void k_dwconv(
    const bf16* q, const bf16* xattn, const float* dwc_w, const float* dwc_b,
    bf16* xsum) {
  __shared__ bf16 sQ[144][200] __attribute__((aligned(16)));
  __shared__ float sW[9][192] __attribute__((aligned(16)));
  const int half = blockIdx.x, b = blockIdx.y;
  const int t = threadIdx.x;
  const int base_n = half ? 112 : 0;

  if (t < 144) {
    const bf16* qs = q + ((size_t)b * SEQ + base_n + t) * CH;
    #pragma unroll
    for (int i2 = 0; i2 < 24; ++i2)
      *(uint4*)&sQ[t][8 * i2] = ((const uint4*)qs)[i2];
  }
  for (int idx = t; idx < 9 * 192; idx += 256) {
    int cc = idx / 9, tap = idx - cc * 9;
    sW[tap][cc] = dwc_w[idx];
  }
  __syncthreads();

  const int nloc = t & 127, chalf = t >> 7;
  const int n = half * 128 + nloc;
  const int ii = n >> 4, jj = n & 15;
  const bf16* xa = xattn + ((size_t)b * SEQ + n) * CH;
  char* xo = (char*)(xsum + ((size_t)b * SEQ + n) * CH);
  const int sw = (n & 7) << 4;
  const int c_base = chalf * 96;

  for (int c0 = c_base; c0 < c_base + 96; c0 += 8) {
    float accv[8];
    {
      const float4* bsrc = (const float4*)(dwc_b + c0);
      float4 b0 = bsrc[0], b1 = bsrc[1];
      accv[0] = b0.x; accv[1] = b0.y; accv[2] = b0.z; accv[3] = b0.w;
      accv[4] = b1.x; accv[5] = b1.y; accv[6] = b1.z; accv[7] = b1.w;
    }
    {
      bf16x8 xv = *(const bf16x8*)(xa + c0);
      #pragma unroll
      for (int j = 0; j < 8; ++j) accv[j] += (float)xv[j];
    }
    #pragma unroll
    for (int di = 0; di < 3; ++di) {
      const int i2 = ii + di - 1;
      if ((unsigned)i2 >= 16u) continue;
      #pragma unroll
      for (int dj = 0; dj < 3; ++dj) {
        const int j2 = jj + dj - 1;
        if ((unsigned)j2 >= 16u) continue;
        const int nn = i2 * 16 + j2 - base_n;
        bf16x8 qv = *(const bf16x8*)&sQ[nn][c0];
        const float4* wv4 = (const float4*)&sW[di * 3 + dj][c0];
        fma8(accv, qv, wv4[0], wv4[1]);
      }
    }
    bf16x8 ob;
    #pragma unroll
    for (int j = 0; j < 8; ++j) ob[j] = (bf16)accv[j];
    *(bf16x8*)(xo + ((2 * c0) ^ sw)) = ob;
  }
}

// ---------------------------------------------------------------------------
extern "C" void kernel_launch(void* const* d_in, const int* in_sizes, int n_in,
                              void* d_out, int out_size, void* d_ws, size_t ws_size,
                              hipStream_t stream) {
  (void)in_sizes; (void)n_in; (void)out_size; (void)ws_size;
  const float* xF1 = (const float*)d_in[0];
  const float* xC2 = (const float*)d_in[1];
  const float* xC1 = (const float*)d_in[2];
  const float* Wq  = (const float*)d_in[3];
  const float* bq  = (const float*)d_in[4];
  const float* Wk  = (const float*)d_in[5];
  const float* bk  = (const float*)d_in[6];
  const float* Wv  = (const float*)d_in[7];
  const float* bv  = (const float*)d_in[8];
  const float* Wa1 = (const float*)d_in[9];
  const float* ba1 = (const float*)d_in[10];
  const float* Wa2 = (const float*)d_in[11];
  const float* ba2 = (const float*)d_in[12];
  const float* an_bias = (const float*)d_in[13];
  const float* na_bias = (const float*)d_in[14];
  const float* ah_bias = (const float*)d_in[15];
  const float* aw_bias = (const float*)d_in[16];
  const float* ha_bias = (const float*)d_in[17];
  const float* wa_bias = (const float*)d_in[18];
  const float* dwc_w = (const float*)d_in[19];
  const float* dwc_b = (const float*)d_in[20];
  const float* Wp  = (const float*)d_in[21];
  const float* bp  = (const float*)d_in[22];

  char* ws = (char*)d_ws;
  size_t off = 0;
  auto nxt = [&](size_t bytes) -> char* {
    char* p = ws + off;
    off = (off + bytes + 255) & ~(size_t)255;
    return p;
  };
  const size_t XSZ = (size_t)BATCH * SEQ * CH;
  const size_t ASZ = ((size_t)BATCH * AG + 64) * CH;

  bf16*  wsW     = (bf16*)nxt(6 * 36864 * sizeof(bf16));
  float* pb      = (float*)nxt(6 * 49 * 256 * sizeof(float));
  float* ab      = (float*)nxt(6 * 256 * 49 * sizeof(float));
  bf16*  pooled1 = (bf16*)nxt(ASZ * sizeof(bf16));
  bf16*  pooled2 = (bf16*)nxt(ASZ * sizeof(bf16));
  bf16*  f1b     = (bf16*)nxt(XSZ * sizeof(bf16));
  bf16*  kin     = (bf16*)nxt(XSZ * sizeof(bf16));
  bf16*  vin     = (bf16*)nxt(XSZ * sizeof(bf16));
  bf16*  qB      = (bf16*)nxt(XSZ * sizeof(bf16));
  bf16*  kB      = (bf16*)nxt(XSZ * sizeof(bf16));
  bf16*  vB      = (bf16*)nxt(XSZ * sizeof(bf16));
  bf16*  a1B     = (bf16*)nxt(ASZ * sizeof(bf16));
  bf16*  a2B     = (bf16*)nxt(ASZ * sizeof(bf16));
  bf16*  xattn   = f1b;   // dead after k_gemm3b
  bf16*  xsum    = kin;   // dead after k_gemm3b

  k_prep<<<1548, 256, 0, stream>>>(Wq, Wk, Wv, Wa1, Wa2, Wp,
                                   an_bias, na_bias, ah_bias, aw_bias,
                                   ha_bias, wa_bias, wsW, pb, ab, a1B, a2B);
  k_combo<<<2048, 256, 0, stream>>>(xF1, xC2, xC1, f1b, kin, vin);
  k_gemm3b<<<dim3(512, 3), 256, 0, stream>>>(f1b, kin, vin, wsW, bq, bk, bv, qB, kB, vB);
  k_pool<<<dim3(BATCH, 2), 192, 0, stream>>>(xC1, xC2, pooled1, pooled2);
  k_gemm2<<<dim3(98, 2), 256, 0, stream>>>(pooled1, pooled2, wsW, ba1, ba2, a1B, a2B);
  k_attn<<<dim3(NH, BATCH), 256, 0, stream>>>(qB, kB, vB, a1B, a2B, pb, ab, xattn);
  k_dwconv<<<dim3(2, BATCH), 256, 0, stream>>>(qB, xattn, dwc_w, dwc_b, xsum);
  k_gemm_out<<<512, 256, 0, stream>>>(xsum, wsW + 5 * 36864, bp, (float*)d_out);
}

// Round 5
// 219.263 us; speedup vs baseline: 1.4230x; 1.1339x over previous
//
#include <hip/hip_runtime.h>

typedef __bf16 bf16;
typedef __bf16 bf16x4 __attribute__((ext_vector_type(4)));
typedef __bf16 bf16x8 __attribute__((ext_vector_type(8)));
typedef float  f32x4  __attribute__((ext_vector_type(4)));

#define DEVI __device__ __forceinline__

static constexpr int   BATCH = 256;
static constexpr int   SEQ   = 256;
static constexpr int   CH    = 192;
static constexpr int   NH    = 6;
static constexpr int   AG    = 49;
static constexpr float QK_SCALE = 0.17677669529663687f;  // 32^-0.5

// ---- adaptive-avg-pool 16 -> 7: inverse bin tables ----
__device__ constexpr int   PPN[16]  = {1,1,2,1,2,1,2,1,1,2,1,2,1,2,1,1};
__device__ constexpr int   PPB0[16] = {0,0,0,1,1,2,2,3,3,3,4,4,5,5,6,6};
__device__ constexpr int   PPB1[16] = {0,0,1,0,2,0,3,0,0,4,0,5,0,6,0,0};
__device__ constexpr float PPW0[16] = {1.f/3.f,1.f/3.f,1.f/3.f,1.f/3.f,1.f/3.f,1.f/3.f,1.f/3.f,0.25f,0.25f,0.25f,
                                       1.f/3.f,1.f/3.f,1.f/3.f,1.f/3.f,1.f/3.f,1.f/3.f};
__device__ constexpr float PPW1[16] = {0.f,0.f,1.f/3.f,0.f,1.f/3.f,0.f,0.25f,0.f,0.f,1.f/3.f,
                                       0.f,1.f/3.f,0.f,1.f/3.f,0.f,0.f};

// ---------------------------------------------------------------------------
#if defined(__has_builtin)
#if __has_builtin(__builtin_amdgcn_global_load_lds)
#define HAVE_GLL 1
#endif
#endif

// async global->LDS 16B: g is PER-LANE source, l is wave-uniform LDS base
// (HW writes l + lane*16).
DEVI void gll16(const void* g, void* l, int lane) {
#ifdef HAVE_GLL
  (void)lane;
  __builtin_amdgcn_global_load_lds(
      (const __attribute__((address_space(1))) void*)g,
      (__attribute__((address_space(3))) void*)l, 16, 0, 0);
#else
  *(uint4*)((char*)l + lane * 16) = *(const uint4*)((const char*)g);
#endif
}

// ---------------------------------------------------------------------------
DEVI float bilin7(const float* m, int i, int j) {
  float sh = (i + 0.5f) * 0.4375f - 0.5f; sh = sh < 0.f ? 0.f : sh;
  float sw = (j + 0.5f) * 0.4375f - 0.5f; sw = sw < 0.f ? 0.f : sw;
  int i0 = (int)sh; if (i0 > 6) i0 = 6;
  int j0 = (int)sw; if (j0 > 6) j0 = 6;
  int i1 = i0 + 1;  if (i1 > 6) i1 = 6;
  int j1 = j0 + 1;  if (j1 > 6) j1 = 6;
  float th = sh - (float)i0, tw = sw - (float)j0;
  float v00 = m[i0*7 + j0], v01 = m[i0*7 + j1];
  float v10 = m[i1*7 + j0], v11 = m[i1*7 + j1];
  return (v00*(1.f-tw) + v01*tw)*(1.f-th) + (v10*(1.f-tw) + v11*tw)*th;
}

// ---------------------------------------------------------------------------
// K1: weights->bf16, pb[h][a][n], ab[h][n][a], zero pads of a1/a2
__global__ void k_prep(const float* Wq, const float* Wk, const float* Wv,
                       const float* Wa1, const float* Wa2, const float* Wp,
                       const float* an_bias, const float* na_bias,
                       const float* ah_bias, const float* aw_bias,
                       const float* ha_bias, const float* wa_bias,
                       bf16* wsW, float* pb, float* ab, bf16* a1, bf16* a2) {
  int gid = blockIdx.x * 256 + threadIdx.x;
  if (gid < 221184) {
    int mi = gid / 36864, r = gid - mi * 36864;
    const float* W = (mi == 0 ? Wq : mi == 1 ? Wk : mi == 2 ? Wv :
                      mi == 3 ? Wa1 : mi == 4 ? Wa2 : Wp);
    wsW[gid] = (bf16)W[r];
  } else if (gid < 296448) {                // pb: [h][49][256]
    int r = gid - 221184;
    int n = r & 255, ha = r >> 8;
    int i = n >> 4, j = n & 15;
    float val = bilin7(an_bias + (size_t)ha * 49, i, j)
              + ah_bias[ha * 16 + i] + aw_bias[ha * 16 + j];
    pb[r] = val;
  } else if (gid < 371712) {                // ab: [h][256][49]
    int r = gid - 296448;
    int a = r % 49, hn = r / 49;
    int n = hn & 255, hh = hn >> 8;
    int i = n >> 4, j = n & 15;
    float val = bilin7(na_bias + (size_t)(hh * 49 + a) * 49, i, j)
              + ha_bias[(hh * 16 + i) * 49 + a] + wa_bias[(hh * 16 + j) * 49 + a];
    ab[r] = val;
  } else if (gid < 396288) {                // zero 64 pad rows of a1,a2
    int r = gid - 371712;
    if (r < 12288) a1[(size_t)12544 * CH + r] = (bf16)0.f;
    else           a2[(size_t)12544 * CH + (r - 12288)] = (bf16)0.f;
  }
}

// ---------------------------------------------------------------------------
// K2: fused combo + q/k/v projection. grid 2048 (32-row tiles), 256 thr.
// Stage fp32 F1/C2/C1 via global_load_lds (72KB), reg-convert to 3 swizzled
// bf16 tiles in-place, then 3 GEMM jobs; outputs restaged for linear stores.
__global__ __launch_bounds__(256, 2) void k_qkv(
    const float* xF1, const float* xC2, const float* xC1,
    const bf16* wsW, const float* bq, const float* bk, const float* bv,
    bf16* qO, bf16* kO, bf16* vO) {
  __shared__ char L[73728] __attribute__((aligned(16)));
  const int tid = threadIdx.x, lane = tid & 63, wid = tid >> 6;
  const int l15 = lane & 15, lg = lane >> 4;
  const int m0 = blockIdx.x * 32;

  // ---- stage 3 x 24576B fp32 tiles (linear, fire-and-forget) ----
  {
    const char* s0 = (const char*)(xF1 + (size_t)m0 * CH);
    const char* s1 = (const char*)(xC2 + (size_t)m0 * CH);
    const char* s2 = (const char*)(xC1 + (size_t)m0 * CH);
    #pragma unroll
    for (int i = 0; i < 6; ++i) {
      const int off = (wid * 6 + i) * 1024;
      gll16(s0 + off + lane * 16, L + off, lane);
    }
    #pragma unroll
    for (int i = 0; i < 6; ++i) {
      const int off = (wid * 6 + i) * 1024;
      gll16(s1 + off + lane * 16, L + 24576 + off, lane);
    }
    #pragma unroll
    for (int i = 0; i < 6; ++i) {
      const int off = (wid * 6 + i) * 1024;
      gll16(s2 + off + lane * 16, L + 49152 + off, lane);
    }
  }
  __syncthreads();

  // ---- read fp32 to regs, convert, write 3 swizzled bf16 tiles at L[0..36863]
  {
    float vF[24], v2[24], v1[24];
    #pragma unroll
    for (int g = 0; g < 6; ++g) {
      const int byt = (tid + 256 * g) * 16;
      *(float4*)&vF[4 * g] = *(const float4*)(L + byt);
      *(float4*)&v2[4 * g] = *(const float4*)(L + 24576 + byt);
      *(float4*)&v1[4 * g] = *(const float4*)(L + 49152 + byt);
    }
    __syncthreads();           // all fp32 in regs; LDS reusable
    #pragma unroll
    for (int g = 0; g < 6; ++g) {
      bf16x4 tq, tk, tv;
      #pragma unroll
      for (int e = 0; e < 4; ++e) {
        const float f = vF[4 * g + e];
        const float d = v2[4 * g + e] - v1[4 * g + e];
        tq[e] = (bf16)f;
        tk[e] = (bf16)(f + d);
        tv[e] = (bf16)d;
      }
      const int f0  = (tid + 256 * g) * 4;
      const int row = f0 / 192, col = f0 - row * 192;
      const int cb2 = col * 2;
      const int byt = row * 384 + ((cb2 & ~15) ^ ((row & 7) << 4)) + (cb2 & 15);
      *(bf16x4*)(L + byt)         = tq;
      *(bf16x4*)(L + 12288 + byt) = tk;
      *(bf16x4*)(L + 24576 + byt) = tv;
    }
  }
  __syncthreads();

  // ---- 3 GEMM jobs ----
  #pragma unroll 1
  for (int job = 0; job < 3; ++job) {
    const bf16*  Wj   = wsW + job * 36864;
    const float* bias = (job == 0 ? bq : job == 1 ? bk : bv);
    bf16*        outp = (job == 0 ? qO : job == 1 ? kO : vO);
    const char*  T    = L + job * 12288;

    f32x4 acc[2][3];
    #pragma unroll
    for (int rt = 0; rt < 2; ++rt)
      #pragma unroll
      for (int ct = 0; ct < 3; ++ct) acc[rt][ct] = f32x4{0.f, 0.f, 0.f, 0.f};

    #pragma unroll
    for (int kk = 0; kk < 6; ++kk) {
      bf16x8 af[2];
      #pragma unroll
      for (int rt = 0; rt < 2; ++rt) {
        const int row = 16 * rt + l15;
        af[rt] = *(const bf16x8*)(T + row * 384 + ((kk * 64 + lg * 16) ^ ((row & 7) << 4)));
      }
      #pragma unroll
      for (int ct = 0; ct < 3; ++ct) {
        const int ncol = 48 * wid + 16 * ct + l15;
        bf16x8 bfr = *(const bf16x8*)&Wj[(size_t)ncol * CH + kk * 32 + 8 * lg];
        acc[0][ct] = __builtin_amdgcn_mfma_f32_16x16x32_bf16(af[0], bfr, acc[0][ct], 0, 0, 0);
        acc[1][ct] = __builtin_amdgcn_mfma_f32_16x16x32_bf16(af[1], bfr, acc[1][ct], 0, 0, 0);
      }
    }
    __syncthreads();           // prior store-phase reads done
    // epilogue -> outreg [32][200] bf16 at offset 36864 (400B row stride)
    #pragma unroll
    for (int ct = 0; ct < 3; ++ct) {
      const int col = 48 * wid + 16 * ct + l15;
      const float bb = bias[col];
      #pragma unroll
      for (int rt = 0; rt < 2; ++rt)
        #pragma unroll
        for (int r = 0; r < 4; ++r) {
          const int row = 16 * rt + 4 * lg + r;
          *(bf16*)(L + 36864 + row * 400 + col * 2) = (bf16)(acc[rt][ct][r] + bb);
        }
    }
    __syncthreads();
    // coalesced linear store: 3 x 16B chunks per thread
    #pragma unroll
    for (int v = 0; v < 3; ++v) {
      const int c   = tid + 256 * v;        // 768 chunks = 32 rows x 24
      const int row = c / 24;
      const int y   = (c - row * 24) * 16;
      bf16x8 vv = *(const bf16x8*)(L + 36864 + row * 400 + y);
      *(bf16x8*)((char*)outp + (size_t)(m0 + row) * 384 + y) = vv;
    }
  }
}

// ---------------------------------------------------------------------------
// K3: adaptive 16x16 -> 7x7 avg pool (static indexing; proven structure).
__global__ __launch_bounds__(192) void k_pool(
    const float* xC1, const float* xC2, bf16* pooled1, bf16* pooled2) {
  const int b = blockIdx.x, which = blockIdx.y, c = threadIdx.x;
  const float* src = (which ? xC2 : xC1) + (size_t)b * SEQ * CH + c;
  bf16* dst = (which ? pooled2 : pooled1) + (size_t)b * AG * CH + c;
  float acc[49];
  #pragma unroll
  for (int a = 0; a < 49; ++a) acc[a] = 0.f;
  #pragma unroll
  for (int i = 0; i < 16; ++i) {
    float jq[7] = {0.f, 0.f, 0.f, 0.f, 0.f, 0.f, 0.f};
    #pragma unroll
    for (int j = 0; j < 16; ++j) {
      const float x = src[(i * 16 + j) * CH];
      jq[PPB0[j]] += PPW0[j] * x;
      if (PPN[j] == 2) jq[PPB1[j]] += PPW1[j] * x;
    }
    {
      const int p0 = PPB0[i]; const float w0 = PPW0[i];
      #pragma unroll
      for (int qq = 0; qq < 7; ++qq) acc[p0 * 7 + qq] += w0 * jq[qq];
    }
    if (PPN[i] == 2) {
      const int p1 = PPB1[i]; const float w1 = PPW1[i];
      #pragma unroll
      for (int qq = 0; qq < 7; ++qq) acc[p1 * 7 + qq] += w1 * jq[qq];
    }
  }
  #pragma unroll
  for (int a = 0; a < 49; ++a) dst[(size_t)a * CH + c] = (bf16)acc[a];
}

// ---------------------------------------------------------------------------
// gemm body for a1/a2 (small, linear inputs, reg staging): tile 128x192
DEVI void gemm_body(const bf16* Asrc, const bf16* W, const float* bias,
                    bf16* outp, int m0, bf16 (*sA)[72]) {
  const int tid = threadIdx.x, lane = tid & 63, wid = tid >> 6;
  const int l15 = lane & 15, lg = lane >> 4;
  const int wr = wid >> 1, wc = wid & 1;
  const int srow = tid >> 1, shalf = tid & 1;

  f32x4 acc[4][6];
  #pragma unroll
  for (int a = 0; a < 4; ++a)
    #pragma unroll
    for (int b2 = 0; b2 < 6; ++b2) acc[a][b2] = f32x4{0.f, 0.f, 0.f, 0.f};

  for (int ks = 0; ks < 3; ++ks) {
    const int k0 = ks * 64;
    const uint4* src = (const uint4*)(Asrc + (size_t)(m0 + srow) * CH + k0 + shalf * 32);
    #pragma unroll
    for (int i2 = 0; i2 < 4; ++i2)
      *(uint4*)&sA[srow][shalf * 32 + 8 * i2] = src[i2];
    __syncthreads();
    #pragma unroll
    for (int kk = 0; kk < 64; kk += 32) {
      bf16x8 af[4];
      #pragma unroll
      for (int rt = 0; rt < 4; ++rt)
        af[rt] = *(const bf16x8*)&sA[64 * wr + 16 * rt + l15][kk + 8 * lg];
      #pragma unroll
      for (int ct = 0; ct < 6; ++ct) {
        const int ncol = 96 * wc + 16 * ct + l15;
        bf16x8 bfr = *(const bf16x8*)&W[(size_t)ncol * CH + k0 + kk + 8 * lg];
        #pragma unroll
        for (int rt = 0; rt < 4; ++rt)
          acc[rt][ct] = __builtin_amdgcn_mfma_f32_16x16x32_bf16(af[rt], bfr, acc[rt][ct], 0, 0, 0);
      }
    }
    __syncthreads();
  }
  #pragma unroll
  for (int ct = 0; ct < 6; ++ct) {
    const int col = 96 * wc + 16 * ct + l15;
    const float bb = bias[col];
    #pragma unroll
    for (int rt = 0; rt < 4; ++rt) {
      const size_t rbase = (size_t)(m0 + 64 * wr + 16 * rt + 4 * lg);
      #pragma unroll
      for (int r = 0; r < 4; ++r)
        outp[(rbase + r) * CH + col] = (bf16)(acc[rt][ct][r] + bb);
    }
  }
}

// K4: a1/a2 projections
__global__ __launch_bounds__(256, 2) void k_gemm2(
    const bf16* pooled1, const bf16* pooled2, const bf16* wsW,
    const float* ba1, const float* ba2, bf16* a1, bf16* a2) {
  __shared__ bf16 sA[128][72] __attribute__((aligned(16)));
  const int m0 = blockIdx.x * 128;
  if (blockIdx.y == 0) gemm_body(pooled1, wsW + 3 * 36864, ba1, a1, m0, sA);
  else                 gemm_body(pooled2, wsW + 4 * 36864, ba2, a2, m0, sA);
}

// ---------------------------------------------------------------------------
// K6: output projection from pre-swizzled xsum via gload_lds; fp32 direct store.
__global__ __launch_bounds__(256, 3) void k_gemm_out(
    const bf16* xsum, const bf16* Wp, const float* bp, float* out) {
  __shared__ char sA[49152] __attribute__((aligned(16)));
  const int tid = threadIdx.x, lane = tid & 63, wid = tid >> 6;
  const int l15 = lane & 15, lg = lane >> 4;
  const int wr = wid >> 1, wc = wid & 1;
  const int m0 = blockIdx.x * 128;

  {
    const char* gsrc = (const char*)xsum + (size_t)m0 * 384;
    #pragma unroll
    for (int i = 0; i < 12; ++i) {
      const int off = (wid * 12 + i) * 1024;
      gll16(gsrc + off + lane * 16, sA + off, lane);
    }
  }
  __syncthreads();

  f32x4 acc[4][6];
  #pragma unroll
  for (int a = 0; a < 4; ++a)
    #pragma unroll
    for (int b2 = 0; b2 < 6; ++b2) acc[a][b2] = f32x4{0.f, 0.f, 0.f, 0.f};

  #pragma unroll
  for (int kk = 0; kk < 6; ++kk) {
    bf16x8 af[4];
    #pragma unroll
    for (int rt = 0; rt < 4; ++rt) {
      const int row = 64 * wr + 16 * rt + l15;
      af[rt] = *(const bf16x8*)(sA + row * 384 + ((kk * 64 + lg * 16) ^ ((row & 7) << 4)));
    }
    #pragma unroll
    for (int ct = 0; ct < 6; ++ct) {
      const int ncol = 96 * wc + 16 * ct + l15;
      bf16x8 bfr = *(const bf16x8*)&Wp[(size_t)ncol * CH + kk * 32 + 8 * lg];
      #pragma unroll
      for (int rt = 0; rt < 4; ++rt)
        acc[rt][ct] = __builtin_amdgcn_mfma_f32_16x16x32_bf16(af[rt], bfr, acc[rt][ct], 0, 0, 0);
    }
  }
  #pragma unroll
  for (int ct = 0; ct < 6; ++ct) {
    const int col = 96 * wc + 16 * ct + l15;
    const float bb = bp[col];
    #pragma unroll
    for (int rt = 0; rt < 4; ++rt)
      #pragma unroll
      for (int r = 0; r < 4; ++r)
        out[(size_t)(m0 + 64 * wr + 16 * rt + 4 * lg + r) * CH + col] = acc[rt][ct][r] + bb;
  }
}

// ---------------------------------------------------------------------------
// K5: fused two-stage agent attention + depthwise conv per (b, h).
// 256 threads = 4 waves. Writes xsum directly (swizzled for k_gemm_out).
__global__ __launch_bounds__(256, 2) void k_attn(
    const bf16* q, const bf16* k, const bf16* v,
    const bf16* a1, const bf16* a2, const float* pb, const float* ab,
    const float* dwc_w, const float* dwc_b, bf16* xsum) {
  const int h = blockIdx.x, b = blockIdx.y;
  __shared__ char uSmem[36864] __attribute__((aligned(16)));   // log1[64][264] | log2[256][72]
  bf16 (*log1)[264] = reinterpret_cast<bf16 (*)[264]>(uSmem);
  bf16 (*log2)[72]  = reinterpret_cast<bf16 (*)[72]>(uSmem);
  __shared__ bf16 sVT[32][264] __attribute__((aligned(16)));
  __shared__ bf16 sAVT[32][72] __attribute__((aligned(16)));
  __shared__ float srow1[64];
  __shared__ float srow2[256];
  __shared__ bf16 xat[256][36] __attribute__((aligned(16)));   // attn out bounce
  __shared__ float sW[9][32];
  __shared__ float dwb[32];

  const int tid = threadIdx.x, lane = tid & 63, wv = tid >> 6;
  const int l15 = lane & 15, lg = lane >> 4;

  const bf16* qb  = q  + (size_t)b * SEQ * CH + h * 32;
  const bf16* kb  = k  + (size_t)b * SEQ * CH + h * 32;
  const bf16* vb  = v  + (size_t)b * SEQ * CH + h * 32;
  const bf16* a1b = a1 + (size_t)b * AG  * CH + h * 32;
  const bf16* a2b = a2 + (size_t)b * AG  * CH + h * 32;

  // ---- conv weights/bias to LDS (early) ----
  for (int idx = tid; idx < 288; idx += 256) {
    const int cl = idx / 9, tap = idx - cl * 9;
    sW[tap][cl] = dwc_w[(32 * h + cl) * 9 + tap];
  }
  if (tid < 32) dwb[tid] = dwc_b[32 * h + tid];

  // ---- stage V^T into LDS ----
  {
    const int p = tid & 127, dg = tid >> 7;
    const bf16* s0 = vb + (size_t)(2 * p) * CH + dg * 16;
    bf16x8 r0a = ((const bf16x8*)s0)[0];
    bf16x8 r0b = ((const bf16x8*)s0)[1];
    bf16x8 r1a = ((const bf16x8*)(s0 + CH))[0];
    bf16x8 r1b = ((const bf16x8*)(s0 + CH))[1];
    #pragma unroll
    for (int j = 0; j < 8; ++j) {
      union { bf16 e[2]; unsigned u; } u0, u1;
      u0.e[0] = r0a[j]; u0.e[1] = r1a[j];
      u1.e[0] = r0b[j]; u1.e[1] = r1b[j];
      *(unsigned*)&sVT[dg * 16 + j][2 * p]     = u0.u;
      *(unsigned*)&sVT[dg * 16 + 8 + j][2 * p] = u1.u;
    }
  }

  // ---- stage-1 logits ----
  {
    bf16x8 afr[4];
    #pragma unroll
    for (int rt = 0; rt < 4; ++rt)
      afr[rt] = *(const bf16x8*)(a2b + (size_t)(16 * rt + l15) * CH + 8 * lg);
    #pragma unroll
    for (int ct = 0; ct < 4; ++ct) {
      const int n = 64 * wv + 16 * ct + l15;
      bf16x8 bfr = *(const bf16x8*)(kb + (size_t)n * CH + 8 * lg);
      #pragma unroll
      for (int rt = 0; rt < 4; ++rt) {
        f32x4 acc = {0.f, 0.f, 0.f, 0.f};
        acc = __builtin_amdgcn_mfma_f32_16x16x32_bf16(afr[rt], bfr, acc, 0, 0, 0);
        #pragma unroll
        for (int r = 0; r < 4; ++r)
          log1[16 * rt + 4 * lg + r][n] = (bf16)acc[r];
      }
    }
  }
  __syncthreads();

  // ---- softmax over n ----
  if (tid < 196) {
    const int a = tid >> 2, qu = tid & 3;
    const float* pbrow = pb + ((size_t)h * AG + a) * SEQ + qu * 64;
    float vbuf[64];
    float m = -1e30f;
    #pragma unroll
    for (int i2 = 0; i2 < 8; ++i2) {
      bf16x8 raw = *(const bf16x8*)&log1[a][qu * 64 + 8 * i2];
      #pragma unroll
      for (int j = 0; j < 8; ++j) {
        float x = QK_SCALE * (float)raw[j] + pbrow[8 * i2 + j];
        vbuf[8 * i2 + j] = x;
        m = fmaxf(m, x);
      }
    }
    m = fmaxf(m, __shfl_xor(m, 1));
    m = fmaxf(m, __shfl_xor(m, 2));
    float s = 0.f;
    #pragma unroll
    for (int i2 = 0; i2 < 8; ++i2) {
      bf16x8 eb;
      #pragma unroll
      for (int j = 0; j < 8; ++j) {
        float e = __expf(vbuf[8 * i2 + j] - m);
        s += e;
        eb[j] = (bf16)e;
      }
      *(bf16x8*)&log1[a][qu * 64 + 8 * i2] = eb;
    }
    s += __shfl_xor(s, 1);
    s += __shfl_xor(s, 2);
    if (qu == 0) srow1[a] = 1.f / s;
  }
  __syncthreads();

  // ---- PV1 ----
  {
    f32x4 acc0 = {0.f, 0.f, 0.f, 0.f}, acc1 = {0.f, 0.f, 0.f, 0.f};
    #pragma unroll
    for (int ksn = 0; ksn < 8; ++ksn) {
      bf16x8 af = *(const bf16x8*)&log1[16 * wv + l15][32 * ksn + 8 * lg];
      bf16x8 b0 = *(const bf16x8*)&sVT[l15][32 * ksn + 8 * lg];
      bf16x8 b1 = *(const bf16x8*)&sVT[16 + l15][32 * ksn + 8 * lg];
      acc0 = __builtin_amdgcn_mfma_f32_16x16x32_bf16(af, b0, acc0, 0, 0, 0);
      acc1 = __builtin_amdgcn_mfma_f32_16x16x32_bf16(af, b1, acc1, 0, 0, 0);
    }
    #pragma unroll
    for (int r = 0; r < 4; ++r) {
      const int a = 16 * wv + 4 * lg + r;
      const float inv = (a < AG) ? srow1[a] : 0.f;
      sAVT[l15][a]      = (bf16)(acc0[r] * inv);
      sAVT[16 + l15][a] = (bf16)(acc1[r] * inv);
    }
  }
  __syncthreads();

  // ---- stage-2 logits ----
  {
    bf16x8 bfr[4];
    #pragma unroll
    for (int ct = 0; ct < 4; ++ct)
      bfr[ct] = *(const bf16x8*)(a1b + (size_t)(16 * ct + l15) * CH + 8 * lg);
    #pragma unroll
    for (int rt = 0; rt < 4; ++rt) {
      bf16x8 af = *(const bf16x8*)(qb + (size_t)(64 * wv + 16 * rt + l15) * CH + 8 * lg);
      #pragma unroll
      for (int ct = 0; ct < 4; ++ct) {
        f32x4 acc = {0.f, 0.f, 0.f, 0.f};
        acc = __builtin_amdgcn_mfma_f32_16x16x32_bf16(af, bfr[ct], acc, 0, 0, 0);
        #pragma unroll
        for (int r = 0; r < 4; ++r)
          log2[64 * wv + 16 * rt + 4 * lg + r][16 * ct + l15] = (bf16)acc[r];
      }
    }
  }
  __syncthreads();

  // ---- softmax over a (49) ----
  {
    const float* abrow = ab + ((size_t)h * SEQ + tid) * AG;
    float vb2[49];
    float m = -1e30f;
    #pragma unroll
    for (int i2 = 0; i2 < 6; ++i2) {
      bf16x8 raw = *(const bf16x8*)&log2[tid][8 * i2];
      #pragma unroll
      for (int j = 0; j < 8; ++j) {
        float x = QK_SCALE * (float)raw[j] + abrow[8 * i2 + j];
        vb2[8 * i2 + j] = x;
        m = fmaxf(m, x);
      }
    }
    {
      float x = QK_SCALE * (float)log2[tid][48] + abrow[48];
      vb2[48] = x;
      m = fmaxf(m, x);
    }
    float s = 0.f;
    #pragma unroll
    for (int i2 = 0; i2 < 8; ++i2) {
      bf16x8 eb;
      #pragma unroll
      for (int j = 0; j < 8; ++j) {
        const int idx = 8 * i2 + j;
        float e = 0.f;
        if (idx < AG) { e = __expf(vb2[idx] - m); }
        s += e;
        eb[j] = (bf16)e;
      }
      *(bf16x8*)&log2[tid][8 * i2] = eb;
    }
    srow2[tid] = 1.f / s;
  }
  __syncthreads();

  // ---- PV2 -> xat (LDS bounce) ----
  {
    bf16x8 bfr[2][2];
    #pragma unroll
    for (int ksn = 0; ksn < 2; ++ksn) {
      bfr[ksn][0] = *(const bf16x8*)&sAVT[l15][32 * ksn + 8 * lg];
      bfr[ksn][1] = *(const bf16x8*)&sAVT[16 + l15][32 * ksn + 8 * lg];
    }
    #pragma unroll
    for (int rt = 0; rt < 4; ++rt) {
      f32x4 acc0 = {0.f, 0.f, 0.f, 0.f}, acc1 = {0.f, 0.f, 0.f, 0.f};
      #pragma unroll
      for (int ksn = 0; ksn < 2; ++ksn) {
        bf16x8 af = *(const bf16x8*)&log2[64 * wv + 16 * rt + l15][32 * ksn + 8 * lg];
        acc0 = __builtin_amdgcn_mfma_f32_16x16x32_bf16(af, bfr[ksn][0], acc0, 0, 0, 0);
        acc1 = __builtin_amdgcn_mfma_f32_16x16x32_bf16(af, bfr[ksn][1], acc1, 0, 0, 0);
      }
      #pragma unroll
      for (int r = 0; r < 4; ++r) {
        const int nq = 64 * wv + 16 * rt + 4 * lg + r;
        const float inv = srow2[nq];
        xat[nq][l15]      = (bf16)(acc0[r] * inv);
        xat[nq][16 + l15] = (bf16)(acc1[r] * inv);
      }
    }
  }
  __syncthreads();

  // ---- depthwise 3x3 conv on q + add attn out; write xsum swizzled ----
  {
    const int n = tid, ii = n >> 4, jj = n & 15;
    float acc[32];
    #pragma unroll
    for (int u = 0; u < 4; ++u) {
      bf16x4 xa0 = *(const bf16x4*)&xat[n][8 * u];
      bf16x4 xa1 = *(const bf16x4*)&xat[n][8 * u + 4];
      #pragma unroll
      for (int e = 0; e < 4; ++e) {
        acc[8 * u + e]     = dwb[8 * u + e]     + (float)xa0[e];
        acc[8 * u + 4 + e] = dwb[8 * u + 4 + e] + (float)xa1[e];
      }
    }
    #pragma unroll
    for (int di = 0; di < 3; ++di) {
      const int i2 = ii + di - 1;
      if ((unsigned)i2 >= 16u) continue;
      #pragma unroll
      for (int dj = 0; dj < 3; ++dj) {
        const int j2 = jj + dj - 1;
        if ((unsigned)j2 >= 16u) continue;
        const int tap = di * 3 + dj;
        const bf16* qr = q + ((size_t)b * SEQ + i2 * 16 + j2) * CH + h * 32;
        #pragma unroll
        for (int u = 0; u < 4; ++u) {
          bf16x8 qv = *(const bf16x8*)(qr + 8 * u);
          const float4* wv4 = (const float4*)&sW[tap][8 * u];
          float4 wa = wv4[0], wb2 = wv4[1];
          acc[8*u+0] += (float)qv[0] * wa.x;  acc[8*u+1] += (float)qv[1] * wa.y;
          acc[8*u+2] += (float)qv[2] * wa.z;  acc[8*u+3] += (float)qv[3] * wa.w;
          acc[8*u+4] += (float)qv[4] * wb2.x; acc[8*u+5] += (float)qv[5] * wb2.y;
          acc[8*u+6] += (float)qv[6] * wb2.z; acc[8*u+7] += (float)qv[7] * wb2.w;
        }
      }
    }
    char* xo = (char*)xsum + (size_t)(b * SEQ + n) * 384;
    const int sw = (n & 7) << 4;
    #pragma unroll
    for (int u = 0; u < 4; ++u) {
      bf16x8 ob;
      #pragma unroll
      for (int e = 0; e < 8; ++e) ob[e] = (bf16)acc[8 * u + e];
      *(bf16x8*)(xo + ((64 * h + 16 * u) ^ sw)) = ob;
    }
  }
}

// ---------------------------------------------------------------------------
extern "C" void kernel_launch(void* const* d_in, const int* in_sizes, int n_in,
                              void* d_out, int out_size, void* d_ws, size_t ws_size,
                              hipStream_t stream) {
  (void)in_sizes; (void)n_in; (void)out_size; (void)ws_size;
  const float* xF1 = (const float*)d_in[0];
  const float* xC2 = (const float*)d_in[1];
  const float* xC1 = (const float*)d_in[2];
  const float* Wq  = (const float*)d_in[3];
  const float* bq  = (const float*)d_in[4];
  const float* Wk  = (const float*)d_in[5];
  const float* bk  = (const float*)d_in[6];
  const float* Wv  = (const float*)d_in[7];
  const float* bv  = (const float*)d_in[8];
  const float* Wa1 = (const float*)d_in[9];
  const float* ba1 = (const float*)d_in[10];
  const float* Wa2 = (const float*)d_in[11];
  const float* ba2 = (const float*)d_in[12];
  const float* an_bias = (const float*)d_in[13];
  const float* na_bias = (const float*)d_in[14];
  const float* ah_bias = (const float*)d_in[15];
  const float* aw_bias = (const float*)d_in[16];
  const float* ha_bias = (const float*)d_in[17];
  const float* wa_bias = (const float*)d_in[18];
  const float* dwc_w = (const float*)d_in[19];
  const float* dwc_b = (const float*)d_in[20];
  const float* Wp  = (const float*)d_in[21];
  const float* bp  = (const float*)d_in[22];

  char* ws = (char*)d_ws;
  size_t off = 0;
  auto nxt = [&](size_t bytes) -> char* {
    char* p = ws + off;
    off = (off + bytes + 255) & ~(size_t)255;
    return p;
  };
  const size_t XSZ = (size_t)BATCH * SEQ * CH;
  const size_t ASZ = ((size_t)BATCH * AG + 64) * CH;

  bf16*  wsW     = (bf16*)nxt(6 * 36864 * sizeof(bf16));
  float* pb      = (float*)nxt(6 * 49 * 256 * sizeof(float));
  float* ab      = (float*)nxt(6 * 256 * 49 * sizeof(float));
  bf16*  pooled1 = (bf16*)nxt(ASZ * sizeof(bf16));
  bf16*  pooled2 = (bf16*)nxt(ASZ * sizeof(bf16));
  bf16*  qB      = (bf16*)nxt(XSZ * sizeof(bf16));
  bf16*  kB      = (bf16*)nxt(XSZ * sizeof(bf16));
  bf16*  vB      = (bf16*)nxt(XSZ * sizeof(bf16));
  bf16*  a1B     = (bf16*)nxt(ASZ * sizeof(bf16));
  bf16*  a2B     = (bf16*)nxt(ASZ * sizeof(bf16));
  bf16*  xsum    = (bf16*)nxt(XSZ * sizeof(bf16));

  k_prep<<<1548, 256, 0, stream>>>(Wq, Wk, Wv, Wa1, Wa2, Wp,
                                   an_bias, na_bias, ah_bias, aw_bias,
                                   ha_bias, wa_bias, wsW, pb, ab, a1B, a2B);
  k_qkv<<<2048, 256, 0, stream>>>(xF1, xC2, xC1, wsW, bq, bk, bv, qB, kB, vB);
  k_pool<<<dim3(BATCH, 2), 192, 0, stream>>>(xC1, xC2, pooled1, pooled2);
  k_gemm2<<<dim3(98, 2), 256, 0, stream>>>(pooled1, pooled2, wsW, ba1, ba2, a1B, a2B);
  k_attn<<<dim3(NH, BATCH), 256, 0, stream>>>(qB, kB, vB, a1B, a2B, pb, ab,
                                              dwc_w, dwc_b, xsum);
  k_gemm_out<<<512, 256, 0, stream>>>(xsum, wsW + 5 * 36864, bp, (float*)d_out);
}